// Round 6
// baseline (881.498 us; speedup 1.0000x reference)
//
#include <hip/hip_runtime.h>
#include <stdint.h>

#define DEV static __device__ __forceinline__

typedef __bf16 bf16x8 __attribute__((ext_vector_type(8)));
typedef float f32x4 __attribute__((ext_vector_type(4)));

constexpr int Bc = 2, Sc = 4096, Dc = 2048, Hc = 16, KVHc = 8, HDc = 128;
constexpr int DQKc = 1024, DVc = 2048;
constexpr int Mc = Bc * Sc;       // 8192 rows
constexpr int NCATc = 6144;       // Q(1024) | K(1024) | V(2048) | Graw(2048)
constexpr int CT = 64;            // scan chunk length
constexpr int NCH = Sc / CT;      // 64 chunks per sequence
constexpr int COEF_STRIDE = 16896; // bytes per chunk-head: M2 8KB | E 8KB | gA 256B | gB 256B
constexpr float EPSc = 1e-6f;

DEV uint16_t f2bf(float f) {
  uint32_t u = __float_as_uint(f);
  u += 0x7FFFu + ((u >> 16) & 1u);   // RNE
  return (uint16_t)(u >> 16);
}
DEV float bf2f(uint16_t h) { return __uint_as_float(((uint32_t)h) << 16); }
DEV float sigmoidf_(float z) { return 1.0f / (1.0f + __expf(-z)); }

DEV void gload16(void* lds, const void* g) {
  auto gp = (const __attribute__((address_space(1))) uint32_t*)(uintptr_t)g;
  auto lp = (__attribute__((address_space(3))) uint32_t*)(uint32_t)(uintptr_t)lds;
  __builtin_amdgcn_global_load_lds(gp, lp, 16, 0, 0);
}

// ---------------- f32 -> bf16 cast ----------------
__global__ __launch_bounds__(256) void cast_kernel(const float* __restrict__ src,
                                                   uint16_t* __restrict__ dst, int n4) {
  int i = blockIdx.x * blockDim.x + threadIdx.x;
  int stride = gridDim.x * blockDim.x;
  for (; i < n4; i += stride) {
    float4 v = *(const float4*)(src + (size_t)i * 4);
    ushort4 o;
    o.x = f2bf(v.x); o.y = f2bf(v.y); o.z = f2bf(v.z); o.w = f2bf(v.w);
    *(ushort4*)(dst + (size_t)i * 4) = o;
  }
}

// ---------------- 256x256 8-phase bf16 GEMM, C = A @ B^T ----------------
// A: (M,K) bf16 rows with stride lda; Bw: (N,K) bf16 stride Kdim; C: (M,N) OutT.
// Slot swizzle: 16B-slot s of row r stored at s ^ ((r>>1)&3); quarter-wave
// bank-groups then spread 8-wide (2 lanes/group = free).
template <typename OutT>
__global__ __launch_bounds__(512, 2) void gemm256_bt(const uint16_t* __restrict__ A,
                                                     const uint16_t* __restrict__ Bw,
                                                     OutT* __restrict__ C, int Ndim, int Kdim,
                                                     int lda) {
  __shared__ uint16_t sT[2][2][2][8192];   // [buf][mat A/B][khalf][256 rows * 32 cols]

  const int nbn = Ndim / 256;
  const int nwg = gridDim.x;
  int q = nwg >> 3, r = nwg & 7;
  int xcd = blockIdx.x & 7, lin = blockIdx.x >> 3;
  int swz = (xcd < r ? xcd * (q + 1) : r * (q + 1) + (xcd - r) * q) + lin;
  const int bm = swz / nbn, bn = swz % nbn;

  const int tid = threadIdx.x;
  const int wid = tid >> 6, lane = tid & 63;
  const int wm = wid >> 2, wn = wid & 3;
  const int lr = lane & 15;
  const int sswz8 = (((lane >> 4) ^ ((lr >> 1) & 3)) * 8);
  const int arow_base = wm * 128 + lr;
  const int brow_base = wn * 64 + lr;

  const uint16_t* Ab = A + (size_t)(bm * 256) * lda;
  const uint16_t* Bb = Bw + (size_t)(bn * 256) * Kdim;
  const int NT = Kdim >> 6;

  // staging: linear slot L = u*512+t; row=L>>2; physical slot L&3 holds
  // logical slot (L&3)^((row>>1)&3) -> pre-swizzled source column.
  int srowA[2];
  int soff[2];
  const int wbase = tid & ~63;
#pragma unroll
  for (int u = 0; u < 2; ++u) {
    int L = u * 512 + tid;
    srowA[u] = L >> 2;
    soff[u] = (((L & 3) ^ ((L >> 3) & 3)) * 8);
  }

  auto STAGE = [&](int buf, int mat, int kh, int kt) {
    const uint16_t* gb = mat == 0 ? Ab : Bb;
    const int ld = mat == 0 ? lda : Kdim;
    uint16_t* rg = &sT[buf][mat][kh][0];
#pragma unroll
    for (int u = 0; u < 2; ++u) {
      const uint16_t* g = gb + (size_t)srowA[u] * ld + kt * 64 + kh * 32 + soff[u];
      gload16(rg + (u * 512 + wbase) * 8, g);
    }
  };

  f32x4 acc[8][4] = {};
  bf16x8 bfr[4];

  // prologue: Kt0 all 4 regions, Kt1 kh0 (A,B)
  STAGE(0, 0, 0, 0); STAGE(0, 1, 0, 0);
  STAGE(0, 0, 1, 0); STAGE(0, 1, 1, 0);
  STAGE(1, 0, 0, 1); STAGE(1, 1, 0, 1);
  asm volatile("s_waitcnt vmcnt(4)" ::: "memory");
  __builtin_amdgcn_s_barrier();

  for (int kt = 0; kt < NT; ++kt) {
    const int buf = kt & 1;
    const uint16_t* aR0 = &sT[buf][0][0][0];
    const uint16_t* bR0 = &sT[buf][1][0][0];
    const uint16_t* aR1 = &sT[buf][0][1][0];
    const uint16_t* bR1 = &sT[buf][1][1][0];

    // ---- P1: k-half 0, m-frags 0..3 (+ all 4 b-frags kh0) ----
    {
      bf16x8 af[4];
#pragma unroll
      for (int m = 0; m < 4; ++m)
        af[m] = *(const bf16x8*)&aR0[(arow_base + m * 16) * 32 + sswz8];
#pragma unroll
      for (int n = 0; n < 4; ++n)
        bfr[n] = *(const bf16x8*)&bR0[(brow_base + n * 16) * 32 + sswz8];
      if (kt + 1 < NT) STAGE(buf ^ 1, 0, 1, kt + 1);
      __builtin_amdgcn_s_setprio(1);
#pragma unroll
      for (int m = 0; m < 4; ++m)
#pragma unroll
        for (int n = 0; n < 4; ++n)
          acc[m][n] = __builtin_amdgcn_mfma_f32_16x16x32_bf16(af[m], bfr[n], acc[m][n], 0, 0, 0);
      __builtin_amdgcn_s_setprio(0);
      __builtin_amdgcn_s_barrier();
    }
    // ---- P2: k-half 0, m-frags 4..7 (b reused) ----
    {
      bf16x8 af[4];
#pragma unroll
      for (int m = 0; m < 4; ++m)
        af[m] = *(const bf16x8*)&aR0[(arow_base + (m + 4) * 16) * 32 + sswz8];
      if (kt + 1 < NT) STAGE(buf ^ 1, 1, 1, kt + 1);
      __builtin_amdgcn_s_setprio(1);
#pragma unroll
      for (int m = 0; m < 4; ++m)
#pragma unroll
        for (int n = 0; n < 4; ++n)
          acc[m + 4][n] = __builtin_amdgcn_mfma_f32_16x16x32_bf16(af[m], bfr[n], acc[m + 4][n], 0, 0, 0);
      __builtin_amdgcn_s_setprio(0);
      __builtin_amdgcn_s_barrier();
    }
    // ---- P3: k-half 1, m-frags 0..3 (+ all 4 b-frags kh1) ----
    {
      bf16x8 af[4];
#pragma unroll
      for (int m = 0; m < 4; ++m)
        af[m] = *(const bf16x8*)&aR1[(arow_base + m * 16) * 32 + sswz8];
#pragma unroll
      for (int n = 0; n < 4; ++n)
        bfr[n] = *(const bf16x8*)&bR1[(brow_base + n * 16) * 32 + sswz8];
      if (kt + 2 < NT) STAGE(buf, 0, 0, kt + 2);
      __builtin_amdgcn_s_setprio(1);
#pragma unroll
      for (int m = 0; m < 4; ++m)
#pragma unroll
        for (int n = 0; n < 4; ++n)
          acc[m][n] = __builtin_amdgcn_mfma_f32_16x16x32_bf16(af[m], bfr[n], acc[m][n], 0, 0, 0);
      __builtin_amdgcn_s_setprio(0);
      __builtin_amdgcn_s_barrier();
    }
    // ---- P4: k-half 1, m-frags 4..7 ----
    {
      bf16x8 af[4];
#pragma unroll
      for (int m = 0; m < 4; ++m)
        af[m] = *(const bf16x8*)&aR1[(arow_base + (m + 4) * 16) * 32 + sswz8];
      if (kt + 2 < NT) STAGE(buf, 1, 0, kt + 2);
      __builtin_amdgcn_s_setprio(1);
#pragma unroll
      for (int m = 0; m < 4; ++m)
#pragma unroll
        for (int n = 0; n < 4; ++n)
          acc[m + 4][n] = __builtin_amdgcn_mfma_f32_16x16x32_bf16(af[m], bfr[n], acc[m + 4][n], 0, 0, 0);
      __builtin_amdgcn_s_setprio(0);
    }
    // ---- K-tile boundary: counted vmcnt, then barrier ----
    if (kt + 1 < NT) {
      if (kt + 2 < NT)
        asm volatile("s_waitcnt vmcnt(4)" ::: "memory");
      else
        asm volatile("s_waitcnt vmcnt(0)" ::: "memory");
      __builtin_amdgcn_s_barrier();
    }
  }

  // epilogue: C write
  const int r0 = (lane >> 4) * 4;
#pragma unroll
  for (int m = 0; m < 8; ++m)
#pragma unroll
    for (int n = 0; n < 4; ++n) {
      int col = bn * 256 + wn * 64 + n * 16 + lr;
#pragma unroll
      for (int j = 0; j < 4; ++j) {
        int row = bm * 256 + wm * 128 + m * 16 + r0 + j;
        float val = acc[m][n][j];
        if constexpr (sizeof(OutT) == 2)
          C[(size_t)row * Ndim + col] = (OutT)f2bf(val);
        else
          C[(size_t)row * Ndim + col] = (OutT)val;
      }
    }
}

// ---------------- alpha/beta (fp32, sigmoid fused, 8 rows/block) ----------------
__global__ __launch_bounds__(256) void alphabeta_kernel(const float* __restrict__ x,
                                                        const float* __restrict__ aw,
                                                        const float* __restrict__ abias,
                                                        const float* __restrict__ bw,
                                                        const float* __restrict__ bbias,
                                                        float* __restrict__ out) {
  __shared__ float xs[8 * Dc];   // 64 KB
  const int row0 = blockIdx.x * 8;
  const float* xp = x + (size_t)row0 * Dc;
  for (int i = threadIdx.x; i < 8 * Dc / 4; i += 256)
    *(float4*)&xs[i * 4] = *(const float4*)(xp + (size_t)i * 4);
  __syncthreads();
  const int r = threadIdx.x >> 5, o = threadIdx.x & 31;
  const float* wrow = (o < 16) ? (aw + (size_t)o * Dc) : (bw + (size_t)(o - 16) * Dc);
  const float* xr = &xs[r * Dc];
  float s = 0.f;
#pragma unroll 4
  for (int k = 0; k < Dc; k += 4) {
    float4 wv = *(const float4*)(wrow + k);
    float4 xv = *(const float4*)(xr + k);
    s += xv.x * wv.x + xv.y * wv.y + xv.z * wv.z + xv.w * wv.w;
  }
  float bias = (o < 16) ? abias[o] : bbias[o - 16];
  float sig = sigmoidf_(s + bias);
  if (o >= 16) sig *= 0.08838834764831845f;   // 1/sqrt(128)
  out[(size_t)(row0 + r) * 32 + o] = sig;
}

// ---------------- causal depthwise conv (k=4) + head RMSNorm ----------------
__global__ __launch_bounds__(256) void convnorm_kernel(const uint16_t* __restrict__ C1,
                                                       const float* __restrict__ qcw,
                                                       const float* __restrict__ kcw,
                                                       const float* __restrict__ nqw,
                                                       const float* __restrict__ nkw,
                                                       uint16_t* __restrict__ Qn,
                                                       uint16_t* __restrict__ Kn) {
  const int wid = blockIdx.x * 4 + (threadIdx.x >> 6);
  const int lane = threadIdx.x & 63;
  const int kvh = wid & 7;
  const int t = (wid >> 3) & (Sc - 1);
  const int b = wid >> 15;
  float qv[2], kv[2];
#pragma unroll
  for (int half = 0; half < 2; ++half) {
    const int c = lane + half * 64;
    const int ch = kvh * HDc + c;
    float qs = 0.f, ks = 0.f;
#pragma unroll
    for (int j = 0; j < 4; ++j) {
      int tt = t - 3 + j;
      if (tt >= 0) {
        size_t rb = (size_t)(b * Sc + tt) * NCATc;
        qs = fmaf(bf2f(C1[rb + ch]), qcw[ch * 4 + j], qs);
        ks = fmaf(bf2f(C1[rb + 1024 + ch]), kcw[ch * 4 + j], ks);
      }
    }
    qv[half] = qs; kv[half] = ks;
  }
  float sq = qv[0] * qv[0] + qv[1] * qv[1];
  float sk = kv[0] * kv[0] + kv[1] * kv[1];
#pragma unroll
  for (int m = 1; m < 64; m <<= 1) { sq += __shfl_xor(sq, m); sk += __shfl_xor(sk, m); }
  const float rq = rsqrtf(sq * (1.f / HDc) + EPSc);
  const float rk = rsqrtf(sk * (1.f / HDc) + EPSc);
#pragma unroll
  for (int half = 0; half < 2; ++half) {
    const int c = lane + half * 64;
    size_t oidx = (size_t)(b * Sc + t) * DQKc + kvh * HDc + c;
    Qn[oidx] = f2bf(nqw[c] * qv[half] * rq);
    Kn[oidx] = f2bf(nkw[c] * kv[half] * rk);
  }
}

// ---------------- per-chunk coefficient precompute (T=64, GQA-deduped) ----------------
// One block per (b,kvh,chunk): KK/QK MFMA computed once, folded for the two
// heads h=2kh, 2kh+1; the two Tinv solves run concurrently on waves 0/1.
// NOTE: no local arrays of LDS-derived pointers (hipcc addrspacecast bug) —
// per-head pointers computed at use-site from hd.
__global__ __launch_bounds__(256) void scores_kernel(const uint16_t* __restrict__ Qn,
                                                     const uint16_t* __restrict__ Kn,
                                                     const float* __restrict__ ab,
                                                     uint8_t* __restrict__ coef) {
  __shared__ __align__(16) char smem[109568];
  uint16_t* sK = (uint16_t*)smem;                  // [64][136]
  uint16_t* sQ = (uint16_t*)(smem + 17408);        // [64][136]
  uint16_t* sM2 = (uint16_t*)smem;                 // alias after solve: [64][72]
  float* Lb = (float*)(smem + 108544);             // [2][64]
  float* bbv = Lb + 128;                           // [2][64]

  // per-head LDS regions (hd in {0,1}): computed, never stored in pointer arrays
  auto Wt_p  = [&](int hd) { return (float*)(smem + hd * 17408); };
  auto Msh_p = [&](int hd) { return (uint16_t*)(smem + 34816 + hd * 18432); };
  auto Msl_p = [&](int hd) { return (uint16_t*)(smem + 44032 + hd * 18432); };
  auto Thh_p = [&](int hd) { return (uint16_t*)(smem + 71680 + hd * 18432); };
  auto Thl_p = [&](int hd) { return (uint16_t*)(smem + 80896 + hd * 18432); };

  const int bid = blockIdx.x;
  const int c = bid & 63, kh = (bid >> 6) & 7, b = bid >> 9;
  const int t0 = c * 64;
  const int tid = threadIdx.x;
  const int w = tid >> 6, l = tid & 63, lr = l & 15, lk = (l >> 4) * 8;
  const int sr = tid >> 2, sq2 = tid & 3;

  auto cb_p = [&](int hd) {
    return coef + (size_t)((b * Hc + kh * 2 + hd) * NCH + c) * COEF_STRIDE;
  };

  {  // stage K,Q (padded rows of 136 u16)
    const size_t rb = (size_t)(b * Sc + t0 + sr) * DQKc + kh * HDc + sq2 * 32;
#pragma unroll
    for (int u = 0; u < 4; ++u) {
      uint4 kv = *(const uint4*)(Kn + rb + u * 8);
      uint4 qv = *(const uint4*)(Qn + rb + u * 8);
      *(uint4*)&sK[sr * 136 + sq2 * 32 + u * 8] = kv;
      *(uint4*)&sQ[sr * 136 + sq2 * 32 + u * 8] = qv;
    }
  }
  if (tid < 128) {  // log-space decays, wave 0 = head 0, wave 1 = head 1
    const int hd = tid >> 6, tt = tid & 63;
    const float* abp = ab + (size_t)(b * Sc + t0 + tt) * 32 + (kh * 2 + hd);
    float av = fmaxf(abp[0], 1e-30f);
    float bv = abp[16];
    float la = log2f(av);
    float L = la;
#pragma unroll
    for (int off = 1; off < 64; off <<= 1) {
      float up = __shfl_up(L, off, 64);
      if (tt >= off) L += up;
    }
    Lb[hd * 64 + tt] = L; bbv[hd * 64 + tt] = bv;
    float* gout = (float*)(cb_p(hd) + 16384);
    gout[tt] = exp2f(L - la);   // gA = G_{i-1}
    gout[64 + tt] = exp2f(L);   // gB = G_i
  }
  __syncthreads();

  // KK = K K^T, QK = Q K^T  (shared by both heads)
  f32x4 kkacc[4] = {}, qkacc[4] = {};
#pragma unroll
  for (int k0 = 0; k0 < 128; k0 += 32) {
    bf16x8 ka = *(const bf16x8*)&sK[(16 * w + lr) * 136 + k0 + lk];
    bf16x8 qa = *(const bf16x8*)&sQ[(16 * w + lr) * 136 + k0 + lk];
#pragma unroll
    for (int n = 0; n < 4; ++n) {
      bf16x8 kb = *(const bf16x8*)&sK[(16 * n + lr) * 136 + k0 + lk];
      kkacc[n] = __builtin_amdgcn_mfma_f32_16x16x32_bf16(ka, kb, kkacc[n], 0, 0, 0);
      qkacc[n] = __builtin_amdgcn_mfma_f32_16x16x32_bf16(qa, kb, qkacc[n], 0, 0, 0);
    }
  }
  __syncthreads();   // sK/sQ dead -> Wt(0)/Wt(1)

  // fold per head
#pragma unroll
  for (int hd = 0; hd < 2; ++hd) {
    float* Wt = Wt_p(hd);
    uint16_t* Mh = Msh_p(hd);
    uint16_t* Ml = Msl_p(hd);
    const float* Lh = Lb + hd * 64;
    const float* bh = bbv + hd * 64;
#pragma unroll
    for (int n = 0; n < 4; ++n)
#pragma unroll
      for (int jj = 0; jj < 4; ++jj) {
        const int i = 16 * w + (l >> 4) * 4 + jj;
        const int j = 16 * n + lr;
        float Li = Lh[i];
        float Lim = (i > 0) ? Lh[(i > 0) ? i - 1 : 0] : 0.f;
        float Lj = Lh[j];
        float bj = bh[j];
        float wv = (j < i) ? exp2f(Lim - Lj) * bj * kkacc[n][jj] : 0.f;
        Wt[j * 68 + i] = wv;                       // W^T
        float ms = (j <= i) ? exp2f(Li - Lj) * bj * qkacc[n][jj] : 0.f;
        uint16_t mh = f2bf(ms);
        Mh[i * 72 + j] = mh;
        Ml[i * 72 + j] = f2bf(ms - bf2f(mh));
      }
  }
  __syncthreads();

  // Tinv = (I + tril(W,-1))^-1 via forward substitution; wave hd solves head hd.
  if (tid < 128) {
    const int hd = tid >> 6, col = tid & 63;
    float* Wt = Wt_p(hd);
    uint16_t* Th = Thh_p(hd);
    uint16_t* Tl = Thl_p(hd);
    float acc[64];
#pragma unroll
    for (int i = 0; i < 64; ++i) acc[i] = 0.f;
#pragma unroll
    for (int ll = 0; ll < 64; ++ll) {
      float xl = ((col == ll) ? 1.f : 0.f) - acc[ll];
      uint16_t xh = f2bf(xl);
      Th[col * 72 + ll] = xh;                      // transposed: [col j][row l]
      Tl[col * 72 + ll] = f2bf(xl - bf2f(xh));
#pragma unroll
      for (int i = ll + 1; i < 64; ++i)
        acc[i] = fmaf(Wt[ll * 68 + i], xl, acc[i]);
    }
  }
  __syncthreads();

  for (int hd = 0; hd < 2; ++hd) {
    uint16_t* Mh = Msh_p(hd);
    uint16_t* Ml = Msl_p(hd);
    uint16_t* Th = Thh_p(hd);
    uint16_t* Tl = Thl_p(hd);
    uint16_t* m2out = (uint16_t*)cb_p(hd);
    uint16_t* eout = (uint16_t*)(cb_p(hd) + 8192);
    const float* Lh = Lb + hd * 64;
    const float* bh = bbv + hd * 64;
    const float L63 = Lh[63];

    // E = diag(gC) * Tinv, packed global stores
    {
      const int i2 = tid >> 2, tq = tid & 3;
      float gC = exp2f(L63 - Lh[i2]) * bh[i2];
      uint32_t pk[8];
#pragma unroll
      for (int p = 0; p < 8; ++p) {
        int t1 = tq * 16 + p * 2;
        float e0 = gC * (bf2f(Th[(t1 + 0) * 72 + i2]) + bf2f(Tl[(t1 + 0) * 72 + i2]));
        float e1 = gC * (bf2f(Th[(t1 + 1) * 72 + i2]) + bf2f(Tl[(t1 + 1) * 72 + i2]));
        pk[p] = (uint32_t)f2bf(e0) | ((uint32_t)f2bf(e1) << 16);
      }
      *(uint4*)(eout + i2 * 64 + tq * 16) = make_uint4(pk[0], pk[1], pk[2], pk[3]);
      *(uint4*)(eout + i2 * 64 + tq * 16 + 8) = make_uint4(pk[4], pk[5], pk[6], pk[7]);
    }

    // M2 = M_s * Tinv  (3-term hi/lo bf16 MFMA)
    f32x4 m2acc[4] = {};
#pragma unroll
    for (int k0 = 0; k0 < 64; k0 += 32) {
      bf16x8 ah = *(const bf16x8*)&Mh[(16 * w + lr) * 72 + k0 + lk];
      bf16x8 al = *(const bf16x8*)&Ml[(16 * w + lr) * 72 + k0 + lk];
#pragma unroll
      for (int n = 0; n < 4; ++n) {
        bf16x8 bhf = *(const bf16x8*)&Th[(16 * n + lr) * 72 + k0 + lk];
        bf16x8 blf = *(const bf16x8*)&Tl[(16 * n + lr) * 72 + k0 + lk];
        m2acc[n] = __builtin_amdgcn_mfma_f32_16x16x32_bf16(ah, bhf, m2acc[n], 0, 0, 0);
        m2acc[n] = __builtin_amdgcn_mfma_f32_16x16x32_bf16(ah, blf, m2acc[n], 0, 0, 0);
        m2acc[n] = __builtin_amdgcn_mfma_f32_16x16x32_bf16(al, bhf, m2acc[n], 0, 0, 0);
      }
    }
#pragma unroll
    for (int n = 0; n < 4; ++n)
#pragma unroll
      for (int jj = 0; jj < 4; ++jj) {
        const int i = 16 * w + (l >> 4) * 4 + jj;
        const int j = 16 * n + lr;
        sM2[i * 72 + j] = f2bf(m2acc[n][jj]);
      }
    __syncthreads();
    {  // packed M2 copy out
      const int i2 = tid >> 2, tq = tid & 3;
      uint4 a0 = *(const uint4*)&sM2[i2 * 72 + tq * 16];
      uint4 a1 = *(const uint4*)&sM2[i2 * 72 + tq * 16 + 8];
      *(uint4*)(m2out + i2 * 64 + tq * 16) = a0;
      *(uint4*)(m2out + i2 * 64 + tq * 16 + 8) = a1;
    }
    __syncthreads();   // protect sM2 before next head
  }
}

// ---------------- MFMA chunked gated delta-rule scan (T=64) ----------------
// Fuses the output gate: O_gated = bf16(sigmoid(Graw) * O) written IN PLACE
// over C1's Graw section (final GEMM reads it with lda=NCATc).
__global__ __launch_bounds__(256) void scan_kernel(const uint16_t* __restrict__ Qn,
                                                   const uint16_t* __restrict__ Kn,
                                                   uint16_t* C1,
                                                   const uint8_t* __restrict__ coef) {
  __shared__ __align__(16) uint16_t Kb[64 * 136];
  __shared__ __align__(16) uint16_t Qb[64 * 136];
  __shared__ __align__(16) uint16_t Ktb[2][128 * 72];  // K^T [dk][t], double-buffered
  __shared__ __align__(16) uint16_t M2b[64 * 72];
  __shared__ __align__(16) uint16_t Eb[64 * 72];
  __shared__ __align__(16) uint16_t Vb[64 * 24];
  __shared__ __align__(16) uint16_t Rt[16 * 72];     // R^T [v][t]
  __shared__ __align__(16) uint16_t D2t[16 * 72];    // D2^T [v][t]
  __shared__ __align__(16) uint16_t Sh[16 * 136];    // S^T hi [v][dk]
  __shared__ __align__(16) uint16_t Slo[16 * 136];   // S^T lo [v][dk]
  __shared__ float gABb[128];                        // gA[64] | gB[64]

  const int bid = blockIdx.x;
  const int kh = bid & 7;
  const int j2 = bid >> 3;
  const int sl = j2 >> 2;
  const int b = (j2 >> 1) & 1;
  const int h = kh * 2 + (j2 & 1);
  const int ch0 = (b * Hc + h) * NCH;

  const int tid = threadIdx.x;
  const int w = tid >> 6, l = tid & 63;
  const int lr = l & 15, lk = (l >> 4) * 8;
  const int row0 = 16 * w + (l >> 4) * 4;
  const int vcol = lr;
  const int sr = tid >> 2, sq2 = tid & 3;

  const size_t kqbase = (size_t)(b * Sc) * DQKc + kh * HDc;
  const size_t vbase = (size_t)(b * Sc) * NCATc + 2048 + h * HDc + sl * 16;
  uint16_t* Gb = C1 + (size_t)(b * Sc) * NCATc + 4096 + h * HDc + sl * 16 + vcol;

  float sreg[2][4] = {};
  uint4 kA[4], kB[4], qA[4], qB[4];
  ushort4 gv0, gv1;

  auto LOADS = [&](int cn, uint4 (&kd)[4], uint4 (&qd)[4], uint4 (&m2d)[2], uint4 (&ed)[2],
                   uint4& vd, float& gd, ushort4& gvd) {
    const size_t rb = kqbase + (size_t)(cn * CT + sr) * DQKc + sq2 * 32;
#pragma unroll
    for (int u = 0; u < 4; ++u) {
      kd[u] = *(const uint4*)(Kn + rb + u * 8);
      qd[u] = *(const uint4*)(Qn + rb + u * 8);
    }
    const uint16_t* cf = (const uint16_t*)(coef + (size_t)(ch0 + cn) * COEF_STRIDE);
#pragma unroll
    for (int e = 0; e < 2; ++e) {
      m2d[e] = *(const uint4*)(cf + sr * 64 + sq2 * 16 + e * 8);
      ed[e] = *(const uint4*)(cf + 4096 + sr * 64 + sq2 * 16 + e * 8);
    }
    if (tid < 128) {
      vd = *(const uint4*)(C1 + vbase + (size_t)(cn * CT + (tid >> 1)) * NCATc + (tid & 1) * 8);
      gd = ((const float*)(cf + 8192))[tid];
    }
    const uint16_t* gpre = Gb + (size_t)(cn * CT) * NCATc;
    gvd.x = gpre[(size_t)(row0 + 0) * NCATc];
    gvd.y = gpre[(size_t)(row0 + 1) * NCATc];
    gvd.z = gpre[(size_t)(row0 + 2) * NCATc];
    gvd.w = gpre[(size_t)(row0 + 3) * NCATc];
  };
  auto WSTAGE = [&](const uint4 (&kd)[4], const uint4 (&qd)[4], const uint4 (&m2d)[2],
                    const uint4 (&ed)[2], const uint4& vd, const float& gd) {
#pragma unroll
    for (int u = 0; u < 4; ++u) {
      *(uint4*)&Kb[sr * 136 + sq2 * 32 + u * 8] = kd[u];
      *(uint4*)&Qb[sr * 136 + sq2 * 32 + u * 8] = qd[u];
    }
#pragma unroll
    for (int e = 0; e < 2; ++e) {
      *(uint4*)&M2b[sr * 72 + sq2 * 16 + e * 8] = m2d[e];
      *(uint4*)&Eb[sr * 72 + sq2 * 16 + e * 8] = ed[e];
    }
    if (tid < 128) {
      *(uint4*)&Vb[(tid >> 1) * 24 + (tid & 1) * 8] = vd;
      gABb[tid] = gd;
    }
  };
  auto SCAT = [&](uint16_t* Kt, const uint4 (&kd)[4], int u) {
    const int c0 = sq2 * 32 + u * 8;
    uint32_t x0 = kd[u].x, x1 = kd[u].y, x2 = kd[u].z, x3 = kd[u].w;
    Kt[(c0 + 0) * 72 + sr] = (uint16_t)x0; Kt[(c0 + 1) * 72 + sr] = (uint16_t)(x0 >> 16);
    Kt[(c0 + 2) * 72 + sr] = (uint16_t)x1; Kt[(c0 + 3) * 72 + sr] = (uint16_t)(x1 >> 16);
    Kt[(c0 + 4) * 72 + sr] = (uint16_t)x2; Kt[(c0 + 5) * 72 + sr] = (uint16_t)(x2 >> 16);
    Kt[(c0 + 6) * 72 + sr] = (uint16_t)x3; Kt[(c0 + 7) * 72 + sr] = (uint16_t)(x3 >> 16);
  };

  auto CHUNK = [&](int c, bool pre, uint4 (&kcur)[4], uint4 (&knxt)[4],
                   uint4 (&qcur)[4], uint4 (&qnxt)[4], ushort4& gvcur, ushort4& gvnxt) {
    uint4 m2d[2], ed[2]; uint4 vd; float gd = 0.f;
    if (pre) LOADS(c + 1, knxt, qnxt, m2d, ed, vd, gd, gvnxt);
    const uint16_t* Ktc = Ktb[c & 1];
    uint16_t* Ktn = Ktb[(c + 1) & 1];

    // --- Phase A: P = K*S, Pq = Q*S, R = V - gA*P ---
    f32x4 accP = {0, 0, 0, 0}, accPq = {0, 0, 0, 0};
#pragma unroll
    for (int k0 = 0; k0 < 128; k0 += 32) {
      bf16x8 ka = *(const bf16x8*)&Kb[(16 * w + lr) * 136 + k0 + lk];
      bf16x8 qa = *(const bf16x8*)&Qb[(16 * w + lr) * 136 + k0 + lk];
      bf16x8 shf = *(const bf16x8*)&Sh[lr * 136 + k0 + lk];
      bf16x8 slf = *(const bf16x8*)&Slo[lr * 136 + k0 + lk];
      accP = __builtin_amdgcn_mfma_f32_16x16x32_bf16(ka, shf, accP, 0, 0, 0);
      accP = __builtin_amdgcn_mfma_f32_16x16x32_bf16(ka, slf, accP, 0, 0, 0);
      accPq = __builtin_amdgcn_mfma_f32_16x16x32_bf16(qa, shf, accPq, 0, 0, 0);
      accPq = __builtin_amdgcn_mfma_f32_16x16x32_bf16(qa, slf, accPq, 0, 0, 0);
    }
    {
      float rv[4];
#pragma unroll
      for (int j = 0; j < 4; ++j) {
        float vv = bf2f(Vb[(row0 + j) * 24 + vcol]);
        float ga = gABb[row0 + j];
        rv[j] = vv - ga * accP[j];
      }
      uint32_t r01 = (uint32_t)f2bf(rv[0]) | ((uint32_t)f2bf(rv[1]) << 16);
      uint32_t r23 = (uint32_t)f2bf(rv[2]) | ((uint32_t)f2bf(rv[3]) << 16);
      *(uint2*)&Rt[vcol * 72 + row0] = make_uint2(r01, r23);
    }
    __syncthreads();

    // --- Phase B: D2 = E*R, O = gB*Pq + M2*R, gated bf16 store (in-place G) ---
    f32x4 accD2 = {0, 0, 0, 0}, accO = {0, 0, 0, 0};
#pragma unroll
    for (int k0 = 0; k0 < 64; k0 += 32) {
      bf16x8 rb8 = *(const bf16x8*)&Rt[lr * 72 + k0 + lk];
      bf16x8 ea = *(const bf16x8*)&Eb[(16 * w + lr) * 72 + k0 + lk];
      bf16x8 ma = *(const bf16x8*)&M2b[(16 * w + lr) * 72 + k0 + lk];
      accD2 = __builtin_amdgcn_mfma_f32_16x16x32_bf16(ea, rb8, accD2, 0, 0, 0);
      accO = __builtin_amdgcn_mfma_f32_16x16x32_bf16(ma, rb8, accO, 0, 0, 0);
    }
    if (pre) { SCAT(Ktn, knxt, 0); SCAT(Ktn, knxt, 1); }
    {
      uint16_t* gp = Gb + (size_t)(c * CT) * NCATc;
      uint16_t gvv[4] = {gvcur.x, gvcur.y, gvcur.z, gvcur.w};
#pragma unroll
      for (int j = 0; j < 4; ++j) {
        float o = gABb[64 + row0 + j] * accPq[j] + accO[j];
        float gg = sigmoidf_(bf2f(gvv[j]));
        gp[(size_t)(row0 + j) * NCATc] = f2bf(o * gg);
      }
      uint32_t d01 = (uint32_t)f2bf(accD2[0]) | ((uint32_t)f2bf(accD2[1]) << 16);
      uint32_t d23 = (uint32_t)f2bf(accD2[2]) | ((uint32_t)f2bf(accD2[3]) << 16);
      *(uint2*)&D2t[vcol * 72 + row0] = make_uint2(d01, d23);
    }
    __syncthreads();

    // --- Phase C: dS = K^T*D2, S = gT*S + dS, stage chunk c+1 ---
    const float gT = gABb[127];
    f32x4 accY[2] = {{0, 0, 0, 0}, {0, 0, 0, 0}};
#pragma unroll
    for (int k0 = 0; k0 < 64; k0 += 32) {
      bf16x8 db = *(const bf16x8*)&D2t[lr * 72 + k0 + lk];
      bf16x8 ka0 = *(const bf16x8*)&Ktc[(32 * w + lr) * 72 + k0 + lk];
      bf16x8 ka1 = *(const bf16x8*)&Ktc[(32 * w + 16 + lr) * 72 + k0 + lk];
      accY[0] = __builtin_amdgcn_mfma_f32_16x16x32_bf16(ka0, db, accY[0], 0, 0, 0);
      accY[1] = __builtin_amdgcn_mfma_f32_16x16x32_bf16(ka1, db, accY[1], 0, 0, 0);
    }
    if (pre) { SCAT(Ktn, knxt, 2); SCAT(Ktn, knxt, 3); }
#pragma unroll
    for (int m = 0; m < 2; ++m) {
      uint16_t hi[4], lo[4];
#pragma unroll
      for (int j = 0; j < 4; ++j) {
        float s = gT * sreg[m][j] + accY[m][j];
        sreg[m][j] = s;
        hi[j] = f2bf(s);
        lo[j] = f2bf(s - bf2f(hi[j]));
      }
      const int dk0 = 32 * w + m * 16 + (l >> 4) * 4;
      *(uint2*)&Sh[vcol * 136 + dk0] =
          make_uint2((uint32_t)hi[0] | ((uint32_t)hi[1] << 16),
                     (uint32_t)hi[2] | ((uint32_t)hi[3] << 16));
      *(uint2*)&Slo[vcol * 136 + dk0] =
          make_uint2((uint32_t)lo[0] | ((uint32_t)lo[1] << 16),
                     (uint32_t)lo[2] | ((uint32_t)lo[3] << 16));
    }
    if (pre) WSTAGE(knxt, qnxt, m2d, ed, vd, gd);
    __syncthreads();
  };

  // prologue: stage chunk 0, zero S, scatter chunk 0's K^T
  {
    uint4 m2d[2], ed[2]; uint4 vd; float gd = 0.f;
    LOADS(0, kA, qA, m2d, ed, vd, gd, gv0);
    WSTAGE(kA, qA, m2d, ed, vd, gd);
#pragma unroll
    for (int u = 0; u < 4; ++u) SCAT(Ktb[0], kA, u);
  }
  for (int i = tid; i < 16 * 136; i += 256) { Sh[i] = 0; Slo[i] = 0; }
  __syncthreads();

  for (int c2 = 0; c2 < NCH; c2 += 2) {
    CHUNK(c2, true, kA, kB, qA, qB, gv0, gv1);
    CHUNK(c2 + 1, c2 + 2 < NCH, kB, kA, qB, qA, gv1, gv0);
  }
}

extern "C" void kernel_launch(void* const* d_in, const int* in_sizes, int n_in,
                              void* d_out, int out_size, void* d_ws, size_t ws_size,
                              hipStream_t stream) {
  (void)in_sizes; (void)n_in; (void)out_size; (void)ws_size;
  const float* x     = (const float*)d_in[0];
  const float* wq    = (const float*)d_in[1];
  const float* wk    = (const float*)d_in[2];
  const float* wv    = (const float*)d_in[3];
  const float* wo    = (const float*)d_in[4];
  const float* qcw   = (const float*)d_in[5];
  const float* kcw   = (const float*)d_in[6];
  const float* aw    = (const float*)d_in[7];
  const float* abias = (const float*)d_in[8];
  const float* bw    = (const float*)d_in[9];
  const float* bbias = (const float*)d_in[10];
  const float* gw    = (const float*)d_in[11];
  const float* nqw   = (const float*)d_in[12];
  const float* nkw   = (const float*)d_in[13];

  // workspace layout (bytes), total ~202 MiB
  uint8_t* ws = (uint8_t*)d_ws;
  uint16_t* xb   = (uint16_t*)(ws);                 //  33,554,432  x bf16
  uint16_t* wcat = (uint16_t*)(ws + 33554432);      //  25,165,824  [wq;wk;wv;g_w] bf16
  uint16_t* wob  = (uint16_t*)(ws + 58720256);      //   8,388,608  wo bf16
  uint16_t* c1   = (uint16_t*)(ws + 67108864);      // 100,663,296  x@Wcat^T bf16 (8192x6144)
  float*    abuf = (float*)   (ws + 167772160);     //   1,048,576  alpha|beta
  uint16_t* qn   = (uint16_t*)(ws + 168820736);     //  16,777,216  normed Q bf16
  uint16_t* kn   = (uint16_t*)(ws + 185597952);     //  16,777,216  normed K bf16
  uint8_t*  cofs = (uint8_t*)ws;                    // coef overlays xb+wcat (dead after GEMM1)

  cast_kernel<<<2048, 256, 0, stream>>>(x, xb, Mc * Dc / 4);
  cast_kernel<<<1024, 256, 0, stream>>>(wq, wcat, DQKc * Dc / 4);
  cast_kernel<<<1024, 256, 0, stream>>>(wk, wcat + DQKc * Dc, DQKc * Dc / 4);
  cast_kernel<<<1024, 256, 0, stream>>>(wv, wcat + 2 * DQKc * Dc, DVc * Dc / 4);
  cast_kernel<<<1024, 256, 0, stream>>>(gw, wcat + 2 * DQKc * Dc + DVc * Dc, DVc * Dc / 4);
  cast_kernel<<<1024, 256, 0, stream>>>(wo, wob, DVc * Dc / 4);

  gemm256_bt<uint16_t><<<768, 512, 0, stream>>>(xb, wcat, c1, NCATc, Dc, Dc);   // QKVG
  alphabeta_kernel<<<1024, 256, 0, stream>>>(x, aw, abias, bw, bbias, abuf);
  convnorm_kernel<<<16384, 256, 0, stream>>>(c1, qcw, kcw, nqw, nkw, qn, kn);
  scores_kernel<<<1024, 256, 0, stream>>>(qn, kn, abuf, cofs);                  // chunk coefs
  scan_kernel<<<256, 256, 0, stream>>>(qn, kn, c1, cofs);                       // gated O -> c1 G-section
  gemm256_bt<float><<<256, 512, 0, stream>>>(c1 + 4096, wob, (float*)d_out, DVc, Dc, NCATc);
}

// Round 7
// 707.801 us; speedup vs baseline: 1.2454x; 1.2454x over previous
//
#include <hip/hip_runtime.h>
#include <stdint.h>

#define DEV static __device__ __forceinline__

typedef __bf16 bf16x8 __attribute__((ext_vector_type(8)));
typedef float f32x4 __attribute__((ext_vector_type(4)));

constexpr int Bc = 2, Sc = 4096, Dc = 2048, Hc = 16, KVHc = 8, HDc = 128;
constexpr int DQKc = 1024, DVc = 2048;
constexpr int Mc = Bc * Sc;       // 8192 rows
constexpr int NCATc = 6144;       // Q(1024) | K(1024) | V(2048) | Graw(2048)
constexpr int CT = 64;            // scan chunk length
constexpr int NCH = Sc / CT;      // 64 chunks per sequence
constexpr int COEF_STRIDE = 16896; // bytes per chunk-head: M2 8KB | E 8KB | gA 256B | gB 256B
constexpr float EPSc = 1e-6f;

DEV uint16_t f2bf(float f) {
  uint32_t u = __float_as_uint(f);
  u += 0x7FFFu + ((u >> 16) & 1u);   // RNE
  return (uint16_t)(u >> 16);
}
DEV float bf2f(uint16_t h) { return __uint_as_float(((uint32_t)h) << 16); }
DEV float sigmoidf_(float z) { return 1.0f / (1.0f + __expf(-z)); }

DEV void gload16(void* lds, const void* g) {
  auto gp = (const __attribute__((address_space(1))) uint32_t*)(uintptr_t)g;
  auto lp = (__attribute__((address_space(3))) uint32_t*)(uint32_t)(uintptr_t)lds;
  __builtin_amdgcn_global_load_lds(gp, lp, 16, 0, 0);
}

// ---------------- f32 -> bf16 cast ----------------
__global__ __launch_bounds__(256) void cast_kernel(const float* __restrict__ src,
                                                   uint16_t* __restrict__ dst, int n4) {
  int i = blockIdx.x * blockDim.x + threadIdx.x;
  int stride = gridDim.x * blockDim.x;
  for (; i < n4; i += stride) {
    float4 v = *(const float4*)(src + (size_t)i * 4);
    ushort4 o;
    o.x = f2bf(v.x); o.y = f2bf(v.y); o.z = f2bf(v.z); o.w = f2bf(v.w);
    *(ushort4*)(dst + (size_t)i * 4) = o;
  }
}

// ---------------- 256x256 8-phase bf16 GEMM, C = A @ B^T ----------------
// A: (M,K) bf16 rows with stride lda; Bw: (N,K) bf16 stride Kdim; C: (M,N) OutT.
// Slot swizzle: 16B-slot s of row r stored at s ^ ((r>>1)&3); quarter-wave
// bank-groups then spread 8-wide (2 lanes/group = free).
template <typename OutT>
__global__ __launch_bounds__(512, 2) void gemm256_bt(const uint16_t* __restrict__ A,
                                                     const uint16_t* __restrict__ Bw,
                                                     OutT* __restrict__ C, int Ndim, int Kdim,
                                                     int lda) {
  __shared__ uint16_t sT[2][2][2][8192];   // [buf][mat A/B][khalf][256 rows * 32 cols]

  const int nbn = Ndim / 256;
  const int nwg = gridDim.x;
  int q = nwg >> 3, r = nwg & 7;
  int xcd = blockIdx.x & 7, lin = blockIdx.x >> 3;
  int swz = (xcd < r ? xcd * (q + 1) : r * (q + 1) + (xcd - r) * q) + lin;
  const int bm = swz / nbn, bn = swz % nbn;

  const int tid = threadIdx.x;
  const int wid = tid >> 6, lane = tid & 63;
  const int wm = wid >> 2, wn = wid & 3;
  const int lr = lane & 15;
  const int sswz8 = (((lane >> 4) ^ ((lr >> 1) & 3)) * 8);
  const int arow_base = wm * 128 + lr;
  const int brow_base = wn * 64 + lr;

  const uint16_t* Ab = A + (size_t)(bm * 256) * lda;
  const uint16_t* Bb = Bw + (size_t)(bn * 256) * Kdim;
  const int NT = Kdim >> 6;

  // staging: linear slot L = u*512+t; row=L>>2; physical slot L&3 holds
  // logical slot (L&3)^((row>>1)&3) -> pre-swizzled source column.
  int srowA[2];
  int soff[2];
  const int wbase = tid & ~63;
#pragma unroll
  for (int u = 0; u < 2; ++u) {
    int L = u * 512 + tid;
    srowA[u] = L >> 2;
    soff[u] = (((L & 3) ^ ((L >> 3) & 3)) * 8);
  }

  auto STAGE = [&](int buf, int mat, int kh, int kt) {
    const uint16_t* gb = mat == 0 ? Ab : Bb;
    const int ld = mat == 0 ? lda : Kdim;
    uint16_t* rg = &sT[buf][mat][kh][0];
#pragma unroll
    for (int u = 0; u < 2; ++u) {
      const uint16_t* g = gb + (size_t)srowA[u] * ld + kt * 64 + kh * 32 + soff[u];
      gload16(rg + (u * 512 + wbase) * 8, g);
    }
  };

  f32x4 acc[8][4] = {};
  bf16x8 bfr[4];

  // prologue: Kt0 all 4 regions, Kt1 kh0 (A,B)
  STAGE(0, 0, 0, 0); STAGE(0, 1, 0, 0);
  STAGE(0, 0, 1, 0); STAGE(0, 1, 1, 0);
  STAGE(1, 0, 0, 1); STAGE(1, 1, 0, 1);
  asm volatile("s_waitcnt vmcnt(4)" ::: "memory");
  __builtin_amdgcn_s_barrier();

  for (int kt = 0; kt < NT; ++kt) {
    const int buf = kt & 1;
    const uint16_t* aR0 = &sT[buf][0][0][0];
    const uint16_t* bR0 = &sT[buf][1][0][0];
    const uint16_t* aR1 = &sT[buf][0][1][0];
    const uint16_t* bR1 = &sT[buf][1][1][0];

    // ---- P1: k-half 0, m-frags 0..3 (+ all 4 b-frags kh0) ----
    {
      bf16x8 af[4];
#pragma unroll
      for (int m = 0; m < 4; ++m)
        af[m] = *(const bf16x8*)&aR0[(arow_base + m * 16) * 32 + sswz8];
#pragma unroll
      for (int n = 0; n < 4; ++n)
        bfr[n] = *(const bf16x8*)&bR0[(brow_base + n * 16) * 32 + sswz8];
      if (kt + 1 < NT) STAGE(buf ^ 1, 0, 1, kt + 1);
      __builtin_amdgcn_s_setprio(1);
#pragma unroll
      for (int m = 0; m < 4; ++m)
#pragma unroll
        for (int n = 0; n < 4; ++n)
          acc[m][n] = __builtin_amdgcn_mfma_f32_16x16x32_bf16(af[m], bfr[n], acc[m][n], 0, 0, 0);
      __builtin_amdgcn_s_setprio(0);
      __builtin_amdgcn_s_barrier();
    }
    // ---- P2: k-half 0, m-frags 4..7 (b reused) ----
    {
      bf16x8 af[4];
#pragma unroll
      for (int m = 0; m < 4; ++m)
        af[m] = *(const bf16x8*)&aR0[(arow_base + (m + 4) * 16) * 32 + sswz8];
      if (kt + 1 < NT) STAGE(buf ^ 1, 1, 1, kt + 1);
      __builtin_amdgcn_s_setprio(1);
#pragma unroll
      for (int m = 0; m < 4; ++m)
#pragma unroll
        for (int n = 0; n < 4; ++n)
          acc[m + 4][n] = __builtin_amdgcn_mfma_f32_16x16x32_bf16(af[m], bfr[n], acc[m + 4][n], 0, 0, 0);
      __builtin_amdgcn_s_setprio(0);
      __builtin_amdgcn_s_barrier();
    }
    // ---- P3: k-half 1, m-frags 0..3 (+ all 4 b-frags kh1) ----
    {
      bf16x8 af[4];
#pragma unroll
      for (int m = 0; m < 4; ++m)
        af[m] = *(const bf16x8*)&aR1[(arow_base + m * 16) * 32 + sswz8];
#pragma unroll
      for (int n = 0; n < 4; ++n)
        bfr[n] = *(const bf16x8*)&bR1[(brow_base + n * 16) * 32 + sswz8];
      if (kt + 2 < NT) STAGE(buf, 0, 0, kt + 2);
      __builtin_amdgcn_s_setprio(1);
#pragma unroll
      for (int m = 0; m < 4; ++m)
#pragma unroll
        for (int n = 0; n < 4; ++n)
          acc[m][n] = __builtin_amdgcn_mfma_f32_16x16x32_bf16(af[m], bfr[n], acc[m][n], 0, 0, 0);
      __builtin_amdgcn_s_setprio(0);
      __builtin_amdgcn_s_barrier();
    }
    // ---- P4: k-half 1, m-frags 4..7 ----
    {
      bf16x8 af[4];
#pragma unroll
      for (int m = 0; m < 4; ++m)
        af[m] = *(const bf16x8*)&aR1[(arow_base + (m + 4) * 16) * 32 + sswz8];
      if (kt + 2 < NT) STAGE(buf, 1, 0, kt + 2);
      __builtin_amdgcn_s_setprio(1);
#pragma unroll
      for (int m = 0; m < 4; ++m)
#pragma unroll
        for (int n = 0; n < 4; ++n)
          acc[m + 4][n] = __builtin_amdgcn_mfma_f32_16x16x32_bf16(af[m], bfr[n], acc[m + 4][n], 0, 0, 0);
      __builtin_amdgcn_s_setprio(0);
    }
    // ---- K-tile boundary: counted vmcnt, then barrier ----
    if (kt + 1 < NT) {
      if (kt + 2 < NT)
        asm volatile("s_waitcnt vmcnt(4)" ::: "memory");
      else
        asm volatile("s_waitcnt vmcnt(0)" ::: "memory");
      __builtin_amdgcn_s_barrier();
    }
  }

  // epilogue: C write
  const int r0 = (lane >> 4) * 4;
#pragma unroll
  for (int m = 0; m < 8; ++m)
#pragma unroll
    for (int n = 0; n < 4; ++n) {
      int col = bn * 256 + wn * 64 + n * 16 + lr;
#pragma unroll
      for (int j = 0; j < 4; ++j) {
        int row = bm * 256 + wm * 128 + m * 16 + r0 + j;
        float val = acc[m][n][j];
        if constexpr (sizeof(OutT) == 2)
          C[(size_t)row * Ndim + col] = (OutT)f2bf(val);
        else
          C[(size_t)row * Ndim + col] = (OutT)val;
      }
    }
}

// ---------------- alpha/beta (fp32, sigmoid fused, 4 rows/block, 8-way K-split) ----------------
// thread (o = tid>>3, lg = tid&7): output o for 4 rows, K split over 8 lanes.
__global__ __launch_bounds__(256) void alphabeta_kernel(const float* __restrict__ x,
                                                        const float* __restrict__ aw,
                                                        const float* __restrict__ abias,
                                                        const float* __restrict__ bw,
                                                        const float* __restrict__ bbias,
                                                        float* __restrict__ out) {
  __shared__ float xs[4 * Dc];   // 32 KB
  const int row0 = blockIdx.x * 4;
  const float* xp = x + (size_t)row0 * Dc;
  for (int i = threadIdx.x; i < 4 * Dc / 4; i += 256)
    *(float4*)&xs[i * 4] = *(const float4*)(xp + (size_t)i * 4);
  __syncthreads();
  const int o = threadIdx.x >> 3, lg = threadIdx.x & 7;
  const float* wrow = (o < 16) ? (aw + (size_t)o * Dc) : (bw + (size_t)(o - 16) * Dc);
  float s0 = 0.f, s1 = 0.f, s2 = 0.f, s3 = 0.f;
  for (int k = lg * 4; k < Dc; k += 32) {
    float4 wv = *(const float4*)(wrow + k);
    float4 x0 = *(const float4*)&xs[k];
    float4 x1 = *(const float4*)&xs[Dc + k];
    float4 x2 = *(const float4*)&xs[2 * Dc + k];
    float4 x3 = *(const float4*)&xs[3 * Dc + k];
    s0 += x0.x * wv.x + x0.y * wv.y + x0.z * wv.z + x0.w * wv.w;
    s1 += x1.x * wv.x + x1.y * wv.y + x1.z * wv.z + x1.w * wv.w;
    s2 += x2.x * wv.x + x2.y * wv.y + x2.z * wv.z + x2.w * wv.w;
    s3 += x3.x * wv.x + x3.y * wv.y + x3.z * wv.z + x3.w * wv.w;
  }
#pragma unroll
  for (int m = 1; m < 8; m <<= 1) {
    s0 += __shfl_xor(s0, m); s1 += __shfl_xor(s1, m);
    s2 += __shfl_xor(s2, m); s3 += __shfl_xor(s3, m);
  }
  if (lg == 0) {
    float bias = (o < 16) ? abias[o] : bbias[o - 16];
    float scale = (o >= 16) ? 0.08838834764831845f : 1.0f;   // 1/sqrt(128)
    out[(size_t)(row0 + 0) * 32 + o] = sigmoidf_(s0 + bias) * scale;
    out[(size_t)(row0 + 1) * 32 + o] = sigmoidf_(s1 + bias) * scale;
    out[(size_t)(row0 + 2) * 32 + o] = sigmoidf_(s2 + bias) * scale;
    out[(size_t)(row0 + 3) * 32 + o] = sigmoidf_(s3 + bias) * scale;
  }
}

// ---------------- causal depthwise conv (k=4) + head RMSNorm ----------------
__global__ __launch_bounds__(256) void convnorm_kernel(const uint16_t* __restrict__ C1,
                                                       const float* __restrict__ qcw,
                                                       const float* __restrict__ kcw,
                                                       const float* __restrict__ nqw,
                                                       const float* __restrict__ nkw,
                                                       uint16_t* __restrict__ Qn,
                                                       uint16_t* __restrict__ Kn) {
  const int wid = blockIdx.x * 4 + (threadIdx.x >> 6);
  const int lane = threadIdx.x & 63;
  const int kvh = wid & 7;
  const int t = (wid >> 3) & (Sc - 1);
  const int b = wid >> 15;
  float qv[2], kv[2];
#pragma unroll
  for (int half = 0; half < 2; ++half) {
    const int c = lane + half * 64;
    const int ch = kvh * HDc + c;
    float qs = 0.f, ks = 0.f;
#pragma unroll
    for (int j = 0; j < 4; ++j) {
      int tt = t - 3 + j;
      if (tt >= 0) {
        size_t rb = (size_t)(b * Sc + tt) * NCATc;
        qs = fmaf(bf2f(C1[rb + ch]), qcw[ch * 4 + j], qs);
        ks = fmaf(bf2f(C1[rb + 1024 + ch]), kcw[ch * 4 + j], ks);
      }
    }
    qv[half] = qs; kv[half] = ks;
  }
  float sq = qv[0] * qv[0] + qv[1] * qv[1];
  float sk = kv[0] * kv[0] + kv[1] * kv[1];
#pragma unroll
  for (int m = 1; m < 64; m <<= 1) { sq += __shfl_xor(sq, m); sk += __shfl_xor(sk, m); }
  const float rq = rsqrtf(sq * (1.f / HDc) + EPSc);
  const float rk = rsqrtf(sk * (1.f / HDc) + EPSc);
#pragma unroll
  for (int half = 0; half < 2; ++half) {
    const int c = lane + half * 64;
    size_t oidx = (size_t)(b * Sc + t) * DQKc + kvh * HDc + c;
    Qn[oidx] = f2bf(nqw[c] * qv[half] * rq);
    Kn[oidx] = f2bf(nkw[c] * kv[half] * rk);
  }
}

// ---------------- per-chunk coefficient precompute (T=64, GQA-deduped) ----------------
// One block per (b,kvh,chunk): KK/QK MFMA computed once, folded for the two
// heads h=2kh, 2kh+1; the two Tinv solves run concurrently on waves 0/1.
// NOTE: no local arrays of LDS-derived pointers (hipcc addrspacecast bug) —
// per-head pointers computed at use-site from hd.
__global__ __launch_bounds__(256) void scores_kernel(const uint16_t* __restrict__ Qn,
                                                     const uint16_t* __restrict__ Kn,
                                                     const float* __restrict__ ab,
                                                     uint8_t* __restrict__ coef) {
  __shared__ __align__(16) char smem[109568];
  uint16_t* sK = (uint16_t*)smem;                  // [64][136]
  uint16_t* sQ = (uint16_t*)(smem + 17408);        // [64][136]
  uint16_t* sM2 = (uint16_t*)smem;                 // alias after solve: [64][72]
  float* Lb = (float*)(smem + 108544);             // [2][64]
  float* bbv = Lb + 128;                           // [2][64]

  // per-head LDS regions (hd in {0,1}): computed, never stored in pointer arrays
  auto Wt_p  = [&](int hd) { return (float*)(smem + hd * 17408); };
  auto Msh_p = [&](int hd) { return (uint16_t*)(smem + 34816 + hd * 18432); };
  auto Msl_p = [&](int hd) { return (uint16_t*)(smem + 44032 + hd * 18432); };
  auto Thh_p = [&](int hd) { return (uint16_t*)(smem + 71680 + hd * 18432); };
  auto Thl_p = [&](int hd) { return (uint16_t*)(smem + 80896 + hd * 18432); };

  const int bid = blockIdx.x;
  const int c = bid & 63, kh = (bid >> 6) & 7, b = bid >> 9;
  const int t0 = c * 64;
  const int tid = threadIdx.x;
  const int w = tid >> 6, l = tid & 63, lr = l & 15, lk = (l >> 4) * 8;
  const int sr = tid >> 2, sq2 = tid & 3;

  auto cb_p = [&](int hd) {
    return coef + (size_t)((b * Hc + kh * 2 + hd) * NCH + c) * COEF_STRIDE;
  };

  {  // stage K,Q (padded rows of 136 u16)
    const size_t rb = (size_t)(b * Sc + t0 + sr) * DQKc + kh * HDc + sq2 * 32;
#pragma unroll
    for (int u = 0; u < 4; ++u) {
      uint4 kv = *(const uint4*)(Kn + rb + u * 8);
      uint4 qv = *(const uint4*)(Qn + rb + u * 8);
      *(uint4*)&sK[sr * 136 + sq2 * 32 + u * 8] = kv;
      *(uint4*)&sQ[sr * 136 + sq2 * 32 + u * 8] = qv;
    }
  }
  if (tid < 128) {  // log-space decays, wave 0 = head 0, wave 1 = head 1
    const int hd = tid >> 6, tt = tid & 63;
    const float* abp = ab + (size_t)(b * Sc + t0 + tt) * 32 + (kh * 2 + hd);
    float av = fmaxf(abp[0], 1e-30f);
    float bv = abp[16];
    float la = log2f(av);
    float L = la;
#pragma unroll
    for (int off = 1; off < 64; off <<= 1) {
      float up = __shfl_up(L, off, 64);
      if (tt >= off) L += up;
    }
    Lb[hd * 64 + tt] = L; bbv[hd * 64 + tt] = bv;
    float* gout = (float*)(cb_p(hd) + 16384);
    gout[tt] = exp2f(L - la);   // gA = G_{i-1}
    gout[64 + tt] = exp2f(L);   // gB = G_i
  }
  __syncthreads();

  // KK = K K^T, QK = Q K^T  (shared by both heads)
  f32x4 kkacc[4] = {}, qkacc[4] = {};
#pragma unroll
  for (int k0 = 0; k0 < 128; k0 += 32) {
    bf16x8 ka = *(const bf16x8*)&sK[(16 * w + lr) * 136 + k0 + lk];
    bf16x8 qa = *(const bf16x8*)&sQ[(16 * w + lr) * 136 + k0 + lk];
#pragma unroll
    for (int n = 0; n < 4; ++n) {
      bf16x8 kb = *(const bf16x8*)&sK[(16 * n + lr) * 136 + k0 + lk];
      kkacc[n] = __builtin_amdgcn_mfma_f32_16x16x32_bf16(ka, kb, kkacc[n], 0, 0, 0);
      qkacc[n] = __builtin_amdgcn_mfma_f32_16x16x32_bf16(qa, kb, qkacc[n], 0, 0, 0);
    }
  }
  __syncthreads();   // sK/sQ dead -> Wt(0)/Wt(1)

  // fold per head
#pragma unroll
  for (int hd = 0; hd < 2; ++hd) {
    float* Wt = Wt_p(hd);
    uint16_t* Mh = Msh_p(hd);
    uint16_t* Ml = Msl_p(hd);
    const float* Lh = Lb + hd * 64;
    const float* bh = bbv + hd * 64;
#pragma unroll
    for (int n = 0; n < 4; ++n)
#pragma unroll
      for (int jj = 0; jj < 4; ++jj) {
        const int i = 16 * w + (l >> 4) * 4 + jj;
        const int j = 16 * n + lr;
        float Li = Lh[i];
        float Lim = (i > 0) ? Lh[(i > 0) ? i - 1 : 0] : 0.f;
        float Lj = Lh[j];
        float bj = bh[j];
        float wv = (j < i) ? exp2f(Lim - Lj) * bj * kkacc[n][jj] : 0.f;
        Wt[j * 68 + i] = wv;                       // W^T
        float ms = (j <= i) ? exp2f(Li - Lj) * bj * qkacc[n][jj] : 0.f;
        uint16_t mh = f2bf(ms);
        Mh[i * 72 + j] = mh;
        Ml[i * 72 + j] = f2bf(ms - bf2f(mh));
      }
  }
  __syncthreads();

  // Tinv = (I + tril(W,-1))^-1 via forward substitution; wave hd solves head hd.
  if (tid < 128) {
    const int hd = tid >> 6, col = tid & 63;
    float* Wt = Wt_p(hd);
    uint16_t* Th = Thh_p(hd);
    uint16_t* Tl = Thl_p(hd);
    float acc[64];
#pragma unroll
    for (int i = 0; i < 64; ++i) acc[i] = 0.f;
#pragma unroll
    for (int ll = 0; ll < 64; ++ll) {
      float xl = ((col == ll) ? 1.f : 0.f) - acc[ll];
      uint16_t xh = f2bf(xl);
      Th[col * 72 + ll] = xh;                      // transposed: [col j][row l]
      Tl[col * 72 + ll] = f2bf(xl - bf2f(xh));
#pragma unroll
      for (int i = ll + 1; i < 64; ++i)
        acc[i] = fmaf(Wt[ll * 68 + i], xl, acc[i]);
    }
  }
  __syncthreads();

  for (int hd = 0; hd < 2; ++hd) {
    uint16_t* Mh = Msh_p(hd);
    uint16_t* Ml = Msl_p(hd);
    uint16_t* Th = Thh_p(hd);
    uint16_t* Tl = Thl_p(hd);
    uint16_t* m2out = (uint16_t*)cb_p(hd);
    uint16_t* eout = (uint16_t*)(cb_p(hd) + 8192);
    const float* Lh = Lb + hd * 64;
    const float* bh = bbv + hd * 64;
    const float L63 = Lh[63];

    // E = diag(gC) * Tinv, packed global stores
    {
      const int i2 = tid >> 2, tq = tid & 3;
      float gC = exp2f(L63 - Lh[i2]) * bh[i2];
      uint32_t pk[8];
#pragma unroll
      for (int p = 0; p < 8; ++p) {
        int t1 = tq * 16 + p * 2;
        float e0 = gC * (bf2f(Th[(t1 + 0) * 72 + i2]) + bf2f(Tl[(t1 + 0) * 72 + i2]));
        float e1 = gC * (bf2f(Th[(t1 + 1) * 72 + i2]) + bf2f(Tl[(t1 + 1) * 72 + i2]));
        pk[p] = (uint32_t)f2bf(e0) | ((uint32_t)f2bf(e1) << 16);
      }
      *(uint4*)(eout + i2 * 64 + tq * 16) = make_uint4(pk[0], pk[1], pk[2], pk[3]);
      *(uint4*)(eout + i2 * 64 + tq * 16 + 8) = make_uint4(pk[4], pk[5], pk[6], pk[7]);
    }

    // M2 = M_s * Tinv  (3-term hi/lo bf16 MFMA)
    f32x4 m2acc[4] = {};
#pragma unroll
    for (int k0 = 0; k0 < 64; k0 += 32) {
      bf16x8 ah = *(const bf16x8*)&Mh[(16 * w + lr) * 72 + k0 + lk];
      bf16x8 al = *(const bf16x8*)&Ml[(16 * w + lr) * 72 + k0 + lk];
#pragma unroll
      for (int n = 0; n < 4; ++n) {
        bf16x8 bhf = *(const bf16x8*)&Th[(16 * n + lr) * 72 + k0 + lk];
        bf16x8 blf = *(const bf16x8*)&Tl[(16 * n + lr) * 72 + k0 + lk];
        m2acc[n] = __builtin_amdgcn_mfma_f32_16x16x32_bf16(ah, bhf, m2acc[n], 0, 0, 0);
        m2acc[n] = __builtin_amdgcn_mfma_f32_16x16x32_bf16(ah, blf, m2acc[n], 0, 0, 0);
        m2acc[n] = __builtin_amdgcn_mfma_f32_16x16x32_bf16(al, bhf, m2acc[n], 0, 0, 0);
      }
    }
#pragma unroll
    for (int n = 0; n < 4; ++n)
#pragma unroll
      for (int jj = 0; jj < 4; ++jj) {
        const int i = 16 * w + (l >> 4) * 4 + jj;
        const int j = 16 * n + lr;
        sM2[i * 72 + j] = f2bf(m2acc[n][jj]);
      }
    __syncthreads();
    {  // packed M2 copy out
      const int i2 = tid >> 2, tq = tid & 3;
      uint4 a0 = *(const uint4*)&sM2[i2 * 72 + tq * 16];
      uint4 a1 = *(const uint4*)&sM2[i2 * 72 + tq * 16 + 8];
      *(uint4*)(m2out + i2 * 64 + tq * 16) = a0;
      *(uint4*)(m2out + i2 * 64 + tq * 16 + 8) = a1;
    }
    __syncthreads();   // protect sM2 before next head
  }
}

// ---------------- MFMA chunked gated delta-rule scan (T=64) ----------------
// Fuses the output gate: O_gated = bf16(sigmoid(Graw) * O) written IN PLACE
// over C1's Graw section (final GEMM reads it with lda=NCATc).
__global__ __launch_bounds__(256) void scan_kernel(const uint16_t* __restrict__ Qn,
                                                   const uint16_t* __restrict__ Kn,
                                                   uint16_t* C1,
                                                   const uint8_t* __restrict__ coef) {
  __shared__ __align__(16) uint16_t Kb[64 * 136];
  __shared__ __align__(16) uint16_t Qb[64 * 136];
  __shared__ __align__(16) uint16_t Ktb[2][128 * 72];  // K^T [dk][t], double-buffered
  __shared__ __align__(16) uint16_t M2b[64 * 72];
  __shared__ __align__(16) uint16_t Eb[64 * 72];
  __shared__ __align__(16) uint16_t Vb[64 * 24];
  __shared__ __align__(16) uint16_t Rt[16 * 72];     // R^T [v][t]
  __shared__ __align__(16) uint16_t D2t[16 * 72];    // D2^T [v][t]
  __shared__ __align__(16) uint16_t Sh[16 * 136];    // S^T hi [v][dk]
  __shared__ __align__(16) uint16_t Slo[16 * 136];   // S^T lo [v][dk]
  __shared__ float gABb[128];                        // gA[64] | gB[64]

  const int bid = blockIdx.x;
  const int kh = bid & 7;
  const int j2 = bid >> 3;
  const int sl = j2 >> 2;
  const int b = (j2 >> 1) & 1;
  const int h = kh * 2 + (j2 & 1);
  const int ch0 = (b * Hc + h) * NCH;

  const int tid = threadIdx.x;
  const int w = tid >> 6, l = tid & 63;
  const int lr = l & 15, lk = (l >> 4) * 8;
  const int row0 = 16 * w + (l >> 4) * 4;
  const int vcol = lr;
  const int sr = tid >> 2, sq2 = tid & 3;

  const size_t kqbase = (size_t)(b * Sc) * DQKc + kh * HDc;
  const size_t vbase = (size_t)(b * Sc) * NCATc + 2048 + h * HDc + sl * 16;
  uint16_t* Gb = C1 + (size_t)(b * Sc) * NCATc + 4096 + h * HDc + sl * 16 + vcol;

  float sreg[2][4] = {};
  uint4 kA[4], kB[4], qA[4], qB[4];
  ushort4 gv0, gv1;

  auto LOADS = [&](int cn, uint4 (&kd)[4], uint4 (&qd)[4], uint4 (&m2d)[2], uint4 (&ed)[2],
                   uint4& vd, float& gd, ushort4& gvd) {
    const size_t rb = kqbase + (size_t)(cn * CT + sr) * DQKc + sq2 * 32;
#pragma unroll
    for (int u = 0; u < 4; ++u) {
      kd[u] = *(const uint4*)(Kn + rb + u * 8);
      qd[u] = *(const uint4*)(Qn + rb + u * 8);
    }
    const uint16_t* cf = (const uint16_t*)(coef + (size_t)(ch0 + cn) * COEF_STRIDE);
#pragma unroll
    for (int e = 0; e < 2; ++e) {
      m2d[e] = *(const uint4*)(cf + sr * 64 + sq2 * 16 + e * 8);
      ed[e] = *(const uint4*)(cf + 4096 + sr * 64 + sq2 * 16 + e * 8);
    }
    if (tid < 128) {
      vd = *(const uint4*)(C1 + vbase + (size_t)(cn * CT + (tid >> 1)) * NCATc + (tid & 1) * 8);
      gd = ((const float*)(cf + 8192))[tid];
    }
    const uint16_t* gpre = Gb + (size_t)(cn * CT) * NCATc;
    gvd.x = gpre[(size_t)(row0 + 0) * NCATc];
    gvd.y = gpre[(size_t)(row0 + 1) * NCATc];
    gvd.z = gpre[(size_t)(row0 + 2) * NCATc];
    gvd.w = gpre[(size_t)(row0 + 3) * NCATc];
  };
  auto WSTAGE = [&](const uint4 (&kd)[4], const uint4 (&qd)[4], const uint4 (&m2d)[2],
                    const uint4 (&ed)[2], const uint4& vd, const float& gd) {
#pragma unroll
    for (int u = 0; u < 4; ++u) {
      *(uint4*)&Kb[sr * 136 + sq2 * 32 + u * 8] = kd[u];
      *(uint4*)&Qb[sr * 136 + sq2 * 32 + u * 8] = qd[u];
    }
#pragma unroll
    for (int e = 0; e < 2; ++e) {
      *(uint4*)&M2b[sr * 72 + sq2 * 16 + e * 8] = m2d[e];
      *(uint4*)&Eb[sr * 72 + sq2 * 16 + e * 8] = ed[e];
    }
    if (tid < 128) {
      *(uint4*)&Vb[(tid >> 1) * 24 + (tid & 1) * 8] = vd;
      gABb[tid] = gd;
    }
  };
  auto SCAT = [&](uint16_t* Kt, const uint4 (&kd)[4], int u) {
    const int c0 = sq2 * 32 + u * 8;
    uint32_t x0 = kd[u].x, x1 = kd[u].y, x2 = kd[u].z, x3 = kd[u].w;
    Kt[(c0 + 0) * 72 + sr] = (uint16_t)x0; Kt[(c0 + 1) * 72 + sr] = (uint16_t)(x0 >> 16);
    Kt[(c0 + 2) * 72 + sr] = (uint16_t)x1; Kt[(c0 + 3) * 72 + sr] = (uint16_t)(x1 >> 16);
    Kt[(c0 + 4) * 72 + sr] = (uint16_t)x2; Kt[(c0 + 5) * 72 + sr] = (uint16_t)(x2 >> 16);
    Kt[(c0 + 6) * 72 + sr] = (uint16_t)x3; Kt[(c0 + 7) * 72 + sr] = (uint16_t)(x3 >> 16);
  };

  auto CHUNK = [&](int c, bool pre, uint4 (&kcur)[4], uint4 (&knxt)[4],
                   uint4 (&qcur)[4], uint4 (&qnxt)[4], ushort4& gvcur, ushort4& gvnxt) {
    uint4 m2d[2], ed[2]; uint4 vd; float gd = 0.f;
    if (pre) LOADS(c + 1, knxt, qnxt, m2d, ed, vd, gd, gvnxt);
    const uint16_t* Ktc = Ktb[c & 1];
    uint16_t* Ktn = Ktb[(c + 1) & 1];

    // --- Phase A: P = K*S, Pq = Q*S, R = V - gA*P ---
    f32x4 accP = {0, 0, 0, 0}, accPq = {0, 0, 0, 0};
#pragma unroll
    for (int k0 = 0; k0 < 128; k0 += 32) {
      bf16x8 ka = *(const bf16x8*)&Kb[(16 * w + lr) * 136 + k0 + lk];
      bf16x8 qa = *(const bf16x8*)&Qb[(16 * w + lr) * 136 + k0 + lk];
      bf16x8 shf = *(const bf16x8*)&Sh[lr * 136 + k0 + lk];
      bf16x8 slf = *(const bf16x8*)&Slo[lr * 136 + k0 + lk];
      accP = __builtin_amdgcn_mfma_f32_16x16x32_bf16(ka, shf, accP, 0, 0, 0);
      accP = __builtin_amdgcn_mfma_f32_16x16x32_bf16(ka, slf, accP, 0, 0, 0);
      accPq = __builtin_amdgcn_mfma_f32_16x16x32_bf16(qa, shf, accPq, 0, 0, 0);
      accPq = __builtin_amdgcn_mfma_f32_16x16x32_bf16(qa, slf, accPq, 0, 0, 0);
    }
    {
      float rv[4];
#pragma unroll
      for (int j = 0; j < 4; ++j) {
        float vv = bf2f(Vb[(row0 + j) * 24 + vcol]);
        float ga = gABb[row0 + j];
        rv[j] = vv - ga * accP[j];
      }
      uint32_t r01 = (uint32_t)f2bf(rv[0]) | ((uint32_t)f2bf(rv[1]) << 16);
      uint32_t r23 = (uint32_t)f2bf(rv[2]) | ((uint32_t)f2bf(rv[3]) << 16);
      *(uint2*)&Rt[vcol * 72 + row0] = make_uint2(r01, r23);
    }
    __syncthreads();

    // --- Phase B: D2 = E*R, O = gB*Pq + M2*R, gated bf16 store (in-place G) ---
    f32x4 accD2 = {0, 0, 0, 0}, accO = {0, 0, 0, 0};
#pragma unroll
    for (int k0 = 0; k0 < 64; k0 += 32) {
      bf16x8 rb8 = *(const bf16x8*)&Rt[lr * 72 + k0 + lk];
      bf16x8 ea = *(const bf16x8*)&Eb[(16 * w + lr) * 72 + k0 + lk];
      bf16x8 ma = *(const bf16x8*)&M2b[(16 * w + lr) * 72 + k0 + lk];
      accD2 = __builtin_amdgcn_mfma_f32_16x16x32_bf16(ea, rb8, accD2, 0, 0, 0);
      accO = __builtin_amdgcn_mfma_f32_16x16x32_bf16(ma, rb8, accO, 0, 0, 0);
    }
    if (pre) { SCAT(Ktn, knxt, 0); SCAT(Ktn, knxt, 1); }
    {
      uint16_t* gp = Gb + (size_t)(c * CT) * NCATc;
      uint16_t gvv[4] = {gvcur.x, gvcur.y, gvcur.z, gvcur.w};
#pragma unroll
      for (int j = 0; j < 4; ++j) {
        float o = gABb[64 + row0 + j] * accPq[j] + accO[j];
        float gg = sigmoidf_(bf2f(gvv[j]));
        gp[(size_t)(row0 + j) * NCATc] = f2bf(o * gg);
      }
      uint32_t d01 = (uint32_t)f2bf(accD2[0]) | ((uint32_t)f2bf(accD2[1]) << 16);
      uint32_t d23 = (uint32_t)f2bf(accD2[2]) | ((uint32_t)f2bf(accD2[3]) << 16);
      *(uint2*)&D2t[vcol * 72 + row0] = make_uint2(d01, d23);
    }
    __syncthreads();

    // --- Phase C: dS = K^T*D2, S = gT*S + dS, stage chunk c+1 ---
    const float gT = gABb[127];
    f32x4 accY[2] = {{0, 0, 0, 0}, {0, 0, 0, 0}};
#pragma unroll
    for (int k0 = 0; k0 < 64; k0 += 32) {
      bf16x8 db = *(const bf16x8*)&D2t[lr * 72 + k0 + lk];
      bf16x8 ka0 = *(const bf16x8*)&Ktc[(32 * w + lr) * 72 + k0 + lk];
      bf16x8 ka1 = *(const bf16x8*)&Ktc[(32 * w + 16 + lr) * 72 + k0 + lk];
      accY[0] = __builtin_amdgcn_mfma_f32_16x16x32_bf16(ka0, db, accY[0], 0, 0, 0);
      accY[1] = __builtin_amdgcn_mfma_f32_16x16x32_bf16(ka1, db, accY[1], 0, 0, 0);
    }
    if (pre) { SCAT(Ktn, knxt, 2); SCAT(Ktn, knxt, 3); }
#pragma unroll
    for (int m = 0; m < 2; ++m) {
      uint16_t hi[4], lo[4];
#pragma unroll
      for (int j = 0; j < 4; ++j) {
        float s = gT * sreg[m][j] + accY[m][j];
        sreg[m][j] = s;
        hi[j] = f2bf(s);
        lo[j] = f2bf(s - bf2f(hi[j]));
      }
      const int dk0 = 32 * w + m * 16 + (l >> 4) * 4;
      *(uint2*)&Sh[vcol * 136 + dk0] =
          make_uint2((uint32_t)hi[0] | ((uint32_t)hi[1] << 16),
                     (uint32_t)hi[2] | ((uint32_t)hi[3] << 16));
      *(uint2*)&Slo[vcol * 136 + dk0] =
          make_uint2((uint32_t)lo[0] | ((uint32_t)lo[1] << 16),
                     (uint32_t)lo[2] | ((uint32_t)lo[3] << 16));
    }
    if (pre) WSTAGE(knxt, qnxt, m2d, ed, vd, gd);
    __syncthreads();
  };

  // prologue: stage chunk 0, zero S, scatter chunk 0's K^T
  {
    uint4 m2d[2], ed[2]; uint4 vd; float gd = 0.f;
    LOADS(0, kA, qA, m2d, ed, vd, gd, gv0);
    WSTAGE(kA, qA, m2d, ed, vd, gd);
#pragma unroll
    for (int u = 0; u < 4; ++u) SCAT(Ktb[0], kA, u);
  }
  for (int i = tid; i < 16 * 136; i += 256) { Sh[i] = 0; Slo[i] = 0; }
  __syncthreads();

  for (int c2 = 0; c2 < NCH; c2 += 2) {
    CHUNK(c2, true, kA, kB, qA, qB, gv0, gv1);
    CHUNK(c2 + 1, c2 + 2 < NCH, kB, kA, qB, qA, gv1, gv0);
  }
}

extern "C" void kernel_launch(void* const* d_in, const int* in_sizes, int n_in,
                              void* d_out, int out_size, void* d_ws, size_t ws_size,
                              hipStream_t stream) {
  (void)in_sizes; (void)n_in; (void)out_size; (void)ws_size;
  const float* x     = (const float*)d_in[0];
  const float* wq    = (const float*)d_in[1];
  const float* wk    = (const float*)d_in[2];
  const float* wv    = (const float*)d_in[3];
  const float* wo    = (const float*)d_in[4];
  const float* qcw   = (const float*)d_in[5];
  const float* kcw   = (const float*)d_in[6];
  const float* aw    = (const float*)d_in[7];
  const float* abias = (const float*)d_in[8];
  const float* bw    = (const float*)d_in[9];
  const float* bbias = (const float*)d_in[10];
  const float* gw    = (const float*)d_in[11];
  const float* nqw   = (const float*)d_in[12];
  const float* nkw   = (const float*)d_in[13];

  // workspace layout (bytes), total ~202 MiB
  uint8_t* ws = (uint8_t*)d_ws;
  uint16_t* xb   = (uint16_t*)(ws);                 //  33,554,432  x bf16
  uint16_t* wcat = (uint16_t*)(ws + 33554432);      //  25,165,824  [wq;wk;wv;g_w] bf16
  uint16_t* wob  = (uint16_t*)(ws + 58720256);      //   8,388,608  wo bf16
  uint16_t* c1   = (uint16_t*)(ws + 67108864);      // 100,663,296  x@Wcat^T bf16 (8192x6144)
  float*    abuf = (float*)   (ws + 167772160);     //   1,048,576  alpha|beta
  uint16_t* qn   = (uint16_t*)(ws + 168820736);     //  16,777,216  normed Q bf16
  uint16_t* kn   = (uint16_t*)(ws + 185597952);     //  16,777,216  normed K bf16
  uint8_t*  cofs = (uint8_t*)ws;                    // coef overlays xb+wcat (dead after GEMM1)

  cast_kernel<<<2048, 256, 0, stream>>>(x, xb, Mc * Dc / 4);
  cast_kernel<<<1024, 256, 0, stream>>>(wq, wcat, DQKc * Dc / 4);
  cast_kernel<<<1024, 256, 0, stream>>>(wk, wcat + DQKc * Dc, DQKc * Dc / 4);
  cast_kernel<<<1024, 256, 0, stream>>>(wv, wcat + 2 * DQKc * Dc, DVc * Dc / 4);
  cast_kernel<<<1024, 256, 0, stream>>>(gw, wcat + 2 * DQKc * Dc + DVc * Dc, DVc * Dc / 4);
  cast_kernel<<<1024, 256, 0, stream>>>(wo, wob, DVc * Dc / 4);

  gemm256_bt<uint16_t><<<768, 512, 0, stream>>>(xb, wcat, c1, NCATc, Dc, Dc);   // QKVG
  alphabeta_kernel<<<2048, 256, 0, stream>>>(x, aw, abias, bw, bbias, abuf);
  convnorm_kernel<<<16384, 256, 0, stream>>>(c1, qcw, kcw, nqw, nkw, qn, kn);
  scores_kernel<<<1024, 256, 0, stream>>>(qn, kn, abuf, cofs);                  // chunk coefs
  scan_kernel<<<256, 256, 0, stream>>>(qn, kn, c1, cofs);                       // gated O -> c1 G-section
  gemm256_bt<float><<<256, 512, 0, stream>>>(c1 + 4096, wob, (float*)d_out, DVc, Dc, NCATc);
}

// Round 8
// 699.042 us; speedup vs baseline: 1.2610x; 1.0125x over previous
//
#include <hip/hip_runtime.h>
#include <stdint.h>

#define DEV static __device__ __forceinline__

typedef __bf16 bf16x8 __attribute__((ext_vector_type(8)));
typedef float f32x4 __attribute__((ext_vector_type(4)));

constexpr int Bc = 2, Sc = 4096, Dc = 2048, Hc = 16, KVHc = 8, HDc = 128;
constexpr int DQKc = 1024, DVc = 2048;
constexpr int Mc = Bc * Sc;       // 8192 rows
constexpr int NCATc = 6144;       // Q(1024) | K(1024) | V(2048) | Graw(2048)
constexpr int CT = 64;            // scan chunk length
constexpr int NCH = Sc / CT;      // 64 chunks per sequence
constexpr int COEF_STRIDE = 16896; // bytes per chunk-head: M2 8KB | E 8KB | gA 256B | gB 256B
constexpr float EPSc = 1e-6f;

DEV uint16_t f2bf(float f) {
  uint32_t u = __float_as_uint(f);
  u += 0x7FFFu + ((u >> 16) & 1u);   // RNE
  return (uint16_t)(u >> 16);
}
DEV float bf2f(uint16_t h) { return __uint_as_float(((uint32_t)h) << 16); }
DEV float sigmoidf_(float z) { return 1.0f / (1.0f + __expf(-z)); }

DEV void gload16(void* lds, const void* g) {
  auto gp = (const __attribute__((address_space(1))) uint32_t*)(uintptr_t)g;
  auto lp = (__attribute__((address_space(3))) uint32_t*)(uint32_t)(uintptr_t)lds;
  __builtin_amdgcn_global_load_lds(gp, lp, 16, 0, 0);
}

// ---------------- f32 -> bf16 cast ----------------
__global__ __launch_bounds__(256) void cast_kernel(const float* __restrict__ src,
                                                   uint16_t* __restrict__ dst, int n4) {
  int i = blockIdx.x * blockDim.x + threadIdx.x;
  int stride = gridDim.x * blockDim.x;
  for (; i < n4; i += stride) {
    float4 v = *(const float4*)(src + (size_t)i * 4);
    ushort4 o;
    o.x = f2bf(v.x); o.y = f2bf(v.y); o.z = f2bf(v.z); o.w = f2bf(v.w);
    *(ushort4*)(dst + (size_t)i * 4) = o;
  }
}

// ---------------- 256x256 8-phase bf16 GEMM, C = A @ B^T ----------------
// A: (M,K) bf16 rows with stride lda; Bw: (N,K) bf16 stride Kdim; C: (M,N) OutT.
// Slot swizzle: 16B-slot s of row r stored at s ^ ((r>>1)&3); quarter-wave
// bank-groups then spread 8-wide (2 lanes/group = free).
template <typename OutT>
__global__ __launch_bounds__(512, 2) void gemm256_bt(const uint16_t* __restrict__ A,
                                                     const uint16_t* __restrict__ Bw,
                                                     OutT* __restrict__ C, int Ndim, int Kdim,
                                                     int lda) {
  __shared__ uint16_t sT[2][2][2][8192];   // [buf][mat A/B][khalf][256 rows * 32 cols]

  const int nbn = Ndim / 256;
  const int nwg = gridDim.x;
  int q = nwg >> 3, r = nwg & 7;
  int xcd = blockIdx.x & 7, lin = blockIdx.x >> 3;
  int swz = (xcd < r ? xcd * (q + 1) : r * (q + 1) + (xcd - r) * q) + lin;
  const int bm = swz / nbn, bn = swz % nbn;

  const int tid = threadIdx.x;
  const int wid = tid >> 6, lane = tid & 63;
  const int wm = wid >> 2, wn = wid & 3;
  const int lr = lane & 15;
  const int sswz8 = (((lane >> 4) ^ ((lr >> 1) & 3)) * 8);
  const int arow_base = wm * 128 + lr;
  const int brow_base = wn * 64 + lr;

  const uint16_t* Ab = A + (size_t)(bm * 256) * lda;
  const uint16_t* Bb = Bw + (size_t)(bn * 256) * Kdim;
  const int NT = Kdim >> 6;

  // staging: linear slot L = u*512+t; row=L>>2; physical slot L&3 holds
  // logical slot (L&3)^((row>>1)&3) -> pre-swizzled source column.
  int srowA[2];
  int soff[2];
  const int wbase = tid & ~63;
#pragma unroll
  for (int u = 0; u < 2; ++u) {
    int L = u * 512 + tid;
    srowA[u] = L >> 2;
    soff[u] = (((L & 3) ^ ((L >> 3) & 3)) * 8);
  }

  auto STAGE = [&](int buf, int mat, int kh, int kt) {
    const uint16_t* gb = mat == 0 ? Ab : Bb;
    const int ld = mat == 0 ? lda : Kdim;
    uint16_t* rg = &sT[buf][mat][kh][0];
#pragma unroll
    for (int u = 0; u < 2; ++u) {
      const uint16_t* g = gb + (size_t)srowA[u] * ld + kt * 64 + kh * 32 + soff[u];
      gload16(rg + (u * 512 + wbase) * 8, g);
    }
  };

  f32x4 acc[8][4] = {};
  bf16x8 bfr[4];

  // prologue: Kt0 all 4 regions, Kt1 kh0 (A,B)
  STAGE(0, 0, 0, 0); STAGE(0, 1, 0, 0);
  STAGE(0, 0, 1, 0); STAGE(0, 1, 1, 0);
  STAGE(1, 0, 0, 1); STAGE(1, 1, 0, 1);
  asm volatile("s_waitcnt vmcnt(4)" ::: "memory");
  __builtin_amdgcn_s_barrier();

  for (int kt = 0; kt < NT; ++kt) {
    const int buf = kt & 1;
    const uint16_t* aR0 = &sT[buf][0][0][0];
    const uint16_t* bR0 = &sT[buf][1][0][0];
    const uint16_t* aR1 = &sT[buf][0][1][0];
    const uint16_t* bR1 = &sT[buf][1][1][0];

    // ---- P1: k-half 0, m-frags 0..3 (+ all 4 b-frags kh0) ----
    {
      bf16x8 af[4];
#pragma unroll
      for (int m = 0; m < 4; ++m)
        af[m] = *(const bf16x8*)&aR0[(arow_base + m * 16) * 32 + sswz8];
#pragma unroll
      for (int n = 0; n < 4; ++n)
        bfr[n] = *(const bf16x8*)&bR0[(brow_base + n * 16) * 32 + sswz8];
      if (kt + 1 < NT) STAGE(buf ^ 1, 0, 1, kt + 1);
      __builtin_amdgcn_s_setprio(1);
#pragma unroll
      for (int m = 0; m < 4; ++m)
#pragma unroll
        for (int n = 0; n < 4; ++n)
          acc[m][n] = __builtin_amdgcn_mfma_f32_16x16x32_bf16(af[m], bfr[n], acc[m][n], 0, 0, 0);
      __builtin_amdgcn_s_setprio(0);
      __builtin_amdgcn_s_barrier();
    }
    // ---- P2: k-half 0, m-frags 4..7 (b reused) ----
    {
      bf16x8 af[4];
#pragma unroll
      for (int m = 0; m < 4; ++m)
        af[m] = *(const bf16x8*)&aR0[(arow_base + (m + 4) * 16) * 32 + sswz8];
      if (kt + 1 < NT) STAGE(buf ^ 1, 1, 1, kt + 1);
      __builtin_amdgcn_s_setprio(1);
#pragma unroll
      for (int m = 0; m < 4; ++m)
#pragma unroll
        for (int n = 0; n < 4; ++n)
          acc[m + 4][n] = __builtin_amdgcn_mfma_f32_16x16x32_bf16(af[m], bfr[n], acc[m + 4][n], 0, 0, 0);
      __builtin_amdgcn_s_setprio(0);
      __builtin_amdgcn_s_barrier();
    }
    // ---- P3: k-half 1, m-frags 0..3 (+ all 4 b-frags kh1) ----
    {
      bf16x8 af[4];
#pragma unroll
      for (int m = 0; m < 4; ++m)
        af[m] = *(const bf16x8*)&aR1[(arow_base + m * 16) * 32 + sswz8];
#pragma unroll
      for (int n = 0; n < 4; ++n)
        bfr[n] = *(const bf16x8*)&bR1[(brow_base + n * 16) * 32 + sswz8];
      if (kt + 2 < NT) STAGE(buf, 0, 0, kt + 2);
      __builtin_amdgcn_s_setprio(1);
#pragma unroll
      for (int m = 0; m < 4; ++m)
#pragma unroll
        for (int n = 0; n < 4; ++n)
          acc[m][n] = __builtin_amdgcn_mfma_f32_16x16x32_bf16(af[m], bfr[n], acc[m][n], 0, 0, 0);
      __builtin_amdgcn_s_setprio(0);
      __builtin_amdgcn_s_barrier();
    }
    // ---- P4: k-half 1, m-frags 4..7 ----
    {
      bf16x8 af[4];
#pragma unroll
      for (int m = 0; m < 4; ++m)
        af[m] = *(const bf16x8*)&aR1[(arow_base + (m + 4) * 16) * 32 + sswz8];
      if (kt + 2 < NT) STAGE(buf, 1, 0, kt + 2);
      __builtin_amdgcn_s_setprio(1);
#pragma unroll
      for (int m = 0; m < 4; ++m)
#pragma unroll
        for (int n = 0; n < 4; ++n)
          acc[m + 4][n] = __builtin_amdgcn_mfma_f32_16x16x32_bf16(af[m], bfr[n], acc[m + 4][n], 0, 0, 0);
      __builtin_amdgcn_s_setprio(0);
    }
    // ---- K-tile boundary: counted vmcnt, then barrier ----
    if (kt + 1 < NT) {
      if (kt + 2 < NT)
        asm volatile("s_waitcnt vmcnt(4)" ::: "memory");
      else
        asm volatile("s_waitcnt vmcnt(0)" ::: "memory");
      __builtin_amdgcn_s_barrier();
    }
  }

  // epilogue: C write
  const int r0 = (lane >> 4) * 4;
#pragma unroll
  for (int m = 0; m < 8; ++m)
#pragma unroll
    for (int n = 0; n < 4; ++n) {
      int col = bn * 256 + wn * 64 + n * 16 + lr;
#pragma unroll
      for (int j = 0; j < 4; ++j) {
        int row = bm * 256 + wm * 128 + m * 16 + r0 + j;
        float val = acc[m][n][j];
        if constexpr (sizeof(OutT) == 2)
          C[(size_t)row * Ndim + col] = (OutT)f2bf(val);
        else
          C[(size_t)row * Ndim + col] = (OutT)val;
      }
    }
}

// ---------------- alpha/beta (fp32, sigmoid fused, 4 rows/block, 8-way K-split) ----------------
__global__ __launch_bounds__(256) void alphabeta_kernel(const float* __restrict__ x,
                                                        const float* __restrict__ aw,
                                                        const float* __restrict__ abias,
                                                        const float* __restrict__ bw,
                                                        const float* __restrict__ bbias,
                                                        float* __restrict__ out) {
  __shared__ float xs[4 * Dc];   // 32 KB
  const int row0 = blockIdx.x * 4;
  const float* xp = x + (size_t)row0 * Dc;
  for (int i = threadIdx.x; i < 4 * Dc / 4; i += 256)
    *(float4*)&xs[i * 4] = *(const float4*)(xp + (size_t)i * 4);
  __syncthreads();
  const int o = threadIdx.x >> 3, lg = threadIdx.x & 7;
  const float* wrow = (o < 16) ? (aw + (size_t)o * Dc) : (bw + (size_t)(o - 16) * Dc);
  float s0 = 0.f, s1 = 0.f, s2 = 0.f, s3 = 0.f;
  for (int k = lg * 4; k < Dc; k += 32) {
    float4 wv = *(const float4*)(wrow + k);
    float4 x0 = *(const float4*)&xs[k];
    float4 x1 = *(const float4*)&xs[Dc + k];
    float4 x2 = *(const float4*)&xs[2 * Dc + k];
    float4 x3 = *(const float4*)&xs[3 * Dc + k];
    s0 += x0.x * wv.x + x0.y * wv.y + x0.z * wv.z + x0.w * wv.w;
    s1 += x1.x * wv.x + x1.y * wv.y + x1.z * wv.z + x1.w * wv.w;
    s2 += x2.x * wv.x + x2.y * wv.y + x2.z * wv.z + x2.w * wv.w;
    s3 += x3.x * wv.x + x3.y * wv.y + x3.z * wv.z + x3.w * wv.w;
  }
#pragma unroll
  for (int m = 1; m < 8; m <<= 1) {
    s0 += __shfl_xor(s0, m); s1 += __shfl_xor(s1, m);
    s2 += __shfl_xor(s2, m); s3 += __shfl_xor(s3, m);
  }
  if (lg == 0) {
    float bias = (o < 16) ? abias[o] : bbias[o - 16];
    float scale = (o >= 16) ? 0.08838834764831845f : 1.0f;   // 1/sqrt(128)
    out[(size_t)(row0 + 0) * 32 + o] = sigmoidf_(s0 + bias) * scale;
    out[(size_t)(row0 + 1) * 32 + o] = sigmoidf_(s1 + bias) * scale;
    out[(size_t)(row0 + 2) * 32 + o] = sigmoidf_(s2 + bias) * scale;
    out[(size_t)(row0 + 3) * 32 + o] = sigmoidf_(s3 + bias) * scale;
  }
}

// ---------------- causal depthwise conv (k=4) + head RMSNorm ----------------
__global__ __launch_bounds__(256) void convnorm_kernel(const uint16_t* __restrict__ C1,
                                                       const float* __restrict__ qcw,
                                                       const float* __restrict__ kcw,
                                                       const float* __restrict__ nqw,
                                                       const float* __restrict__ nkw,
                                                       uint16_t* __restrict__ Qn,
                                                       uint16_t* __restrict__ Kn) {
  const int wid = blockIdx.x * 4 + (threadIdx.x >> 6);
  const int lane = threadIdx.x & 63;
  const int kvh = wid & 7;
  const int t = (wid >> 3) & (Sc - 1);
  const int b = wid >> 15;
  float qv[2], kv[2];
#pragma unroll
  for (int half = 0; half < 2; ++half) {
    const int c = lane + half * 64;
    const int ch = kvh * HDc + c;
    float qs = 0.f, ks = 0.f;
#pragma unroll
    for (int j = 0; j < 4; ++j) {
      int tt = t - 3 + j;
      if (tt >= 0) {
        size_t rb = (size_t)(b * Sc + tt) * NCATc;
        qs = fmaf(bf2f(C1[rb + ch]), qcw[ch * 4 + j], qs);
        ks = fmaf(bf2f(C1[rb + 1024 + ch]), kcw[ch * 4 + j], ks);
      }
    }
    qv[half] = qs; kv[half] = ks;
  }
  float sq = qv[0] * qv[0] + qv[1] * qv[1];
  float sk = kv[0] * kv[0] + kv[1] * kv[1];
#pragma unroll
  for (int m = 1; m < 64; m <<= 1) { sq += __shfl_xor(sq, m); sk += __shfl_xor(sk, m); }
  const float rq = rsqrtf(sq * (1.f / HDc) + EPSc);
  const float rk = rsqrtf(sk * (1.f / HDc) + EPSc);
#pragma unroll
  for (int half = 0; half < 2; ++half) {
    const int c = lane + half * 64;
    size_t oidx = (size_t)(b * Sc + t) * DQKc + kvh * HDc + c;
    Qn[oidx] = f2bf(nqw[c] * qv[half] * rq);
    Kn[oidx] = f2bf(nkw[c] * kv[half] * rk);
  }
}

// ---------------- per-chunk coefficient precompute (T=64, GQA-deduped) ----------------
__global__ __launch_bounds__(256) void scores_kernel(const uint16_t* __restrict__ Qn,
                                                     const uint16_t* __restrict__ Kn,
                                                     const float* __restrict__ ab,
                                                     uint8_t* __restrict__ coef) {
  __shared__ __align__(16) char smem[109568];
  uint16_t* sK = (uint16_t*)smem;                  // [64][136]
  uint16_t* sQ = (uint16_t*)(smem + 17408);        // [64][136]
  uint16_t* sM2 = (uint16_t*)smem;                 // alias after solve: [64][72]
  float* Lb = (float*)(smem + 108544);             // [2][64]
  float* bbv = Lb + 128;                           // [2][64]

  auto Wt_p  = [&](int hd) { return (float*)(smem + hd * 17408); };
  auto Msh_p = [&](int hd) { return (uint16_t*)(smem + 34816 + hd * 18432); };
  auto Msl_p = [&](int hd) { return (uint16_t*)(smem + 44032 + hd * 18432); };
  auto Thh_p = [&](int hd) { return (uint16_t*)(smem + 71680 + hd * 18432); };
  auto Thl_p = [&](int hd) { return (uint16_t*)(smem + 80896 + hd * 18432); };

  const int bid = blockIdx.x;
  const int c = bid & 63, kh = (bid >> 6) & 7, b = bid >> 9;
  const int t0 = c * 64;
  const int tid = threadIdx.x;
  const int w = tid >> 6, l = tid & 63, lr = l & 15, lk = (l >> 4) * 8;
  const int sr = tid >> 2, sq2 = tid & 3;

  auto cb_p = [&](int hd) {
    return coef + (size_t)((b * Hc + kh * 2 + hd) * NCH + c) * COEF_STRIDE;
  };

  {  // stage K,Q (padded rows of 136 u16)
    const size_t rb = (size_t)(b * Sc + t0 + sr) * DQKc + kh * HDc + sq2 * 32;
#pragma unroll
    for (int u = 0; u < 4; ++u) {
      uint4 kv = *(const uint4*)(Kn + rb + u * 8);
      uint4 qv = *(const uint4*)(Qn + rb + u * 8);
      *(uint4*)&sK[sr * 136 + sq2 * 32 + u * 8] = kv;
      *(uint4*)&sQ[sr * 136 + sq2 * 32 + u * 8] = qv;
    }
  }
  if (tid < 128) {  // log-space decays, wave 0 = head 0, wave 1 = head 1
    const int hd = tid >> 6, tt = tid & 63;
    const float* abp = ab + (size_t)(b * Sc + t0 + tt) * 32 + (kh * 2 + hd);
    float av = fmaxf(abp[0], 1e-30f);
    float bv = abp[16];
    float la = log2f(av);
    float L = la;
#pragma unroll
    for (int off = 1; off < 64; off <<= 1) {
      float up = __shfl_up(L, off, 64);
      if (tt >= off) L += up;
    }
    Lb[hd * 64 + tt] = L; bbv[hd * 64 + tt] = bv;
    float* gout = (float*)(cb_p(hd) + 16384);
    gout[tt] = exp2f(L - la);   // gA = G_{i-1}
    gout[64 + tt] = exp2f(L);   // gB = G_i
  }
  __syncthreads();

  // KK = K K^T, QK = Q K^T  (shared by both heads)
  f32x4 kkacc[4] = {}, qkacc[4] = {};
#pragma unroll
  for (int k0 = 0; k0 < 128; k0 += 32) {
    bf16x8 ka = *(const bf16x8*)&sK[(16 * w + lr) * 136 + k0 + lk];
    bf16x8 qa = *(const bf16x8*)&sQ[(16 * w + lr) * 136 + k0 + lk];
#pragma unroll
    for (int n = 0; n < 4; ++n) {
      bf16x8 kb = *(const bf16x8*)&sK[(16 * n + lr) * 136 + k0 + lk];
      kkacc[n] = __builtin_amdgcn_mfma_f32_16x16x32_bf16(ka, kb, kkacc[n], 0, 0, 0);
      qkacc[n] = __builtin_amdgcn_mfma_f32_16x16x32_bf16(qa, kb, qkacc[n], 0, 0, 0);
    }
  }
  __syncthreads();   // sK/sQ dead -> Wt(0)/Wt(1)

  // fold per head
#pragma unroll
  for (int hd = 0; hd < 2; ++hd) {
    float* Wt = Wt_p(hd);
    uint16_t* Mh = Msh_p(hd);
    uint16_t* Ml = Msl_p(hd);
    const float* Lh = Lb + hd * 64;
    const float* bh = bbv + hd * 64;
#pragma unroll
    for (int n = 0; n < 4; ++n)
#pragma unroll
      for (int jj = 0; jj < 4; ++jj) {
        const int i = 16 * w + (l >> 4) * 4 + jj;
        const int j = 16 * n + lr;
        float Li = Lh[i];
        float Lim = (i > 0) ? Lh[(i > 0) ? i - 1 : 0] : 0.f;
        float Lj = Lh[j];
        float bj = bh[j];
        float wv = (j < i) ? exp2f(Lim - Lj) * bj * kkacc[n][jj] : 0.f;
        Wt[j * 68 + i] = wv;                       // W^T
        float ms = (j <= i) ? exp2f(Li - Lj) * bj * qkacc[n][jj] : 0.f;
        uint16_t mh = f2bf(ms);
        Mh[i * 72 + j] = mh;
        Ml[i * 72 + j] = f2bf(ms - bf2f(mh));
      }
  }
  __syncthreads();

  // Tinv = (I + tril(W,-1))^-1 via forward substitution; wave hd solves head hd.
  if (tid < 128) {
    const int hd = tid >> 6, col = tid & 63;
    float* Wt = Wt_p(hd);
    uint16_t* Th = Thh_p(hd);
    uint16_t* Tl = Thl_p(hd);
    float acc[64];
#pragma unroll
    for (int i = 0; i < 64; ++i) acc[i] = 0.f;
#pragma unroll
    for (int ll = 0; ll < 64; ++ll) {
      float xl = ((col == ll) ? 1.f : 0.f) - acc[ll];
      uint16_t xh = f2bf(xl);
      Th[col * 72 + ll] = xh;                      // transposed: [col j][row l]
      Tl[col * 72 + ll] = f2bf(xl - bf2f(xh));
#pragma unroll
      for (int i = ll + 1; i < 64; ++i)
        acc[i] = fmaf(Wt[ll * 68 + i], xl, acc[i]);
    }
  }
  __syncthreads();

  for (int hd = 0; hd < 2; ++hd) {
    uint16_t* Mh = Msh_p(hd);
    uint16_t* Ml = Msl_p(hd);
    uint16_t* Th = Thh_p(hd);
    uint16_t* Tl = Thl_p(hd);
    uint16_t* m2out = (uint16_t*)cb_p(hd);
    uint16_t* eout = (uint16_t*)(cb_p(hd) + 8192);
    const float* Lh = Lb + hd * 64;
    const float* bh = bbv + hd * 64;
    const float L63 = Lh[63];

    // E = diag(gC) * Tinv, packed global stores
    {
      const int i2 = tid >> 2, tq = tid & 3;
      float gC = exp2f(L63 - Lh[i2]) * bh[i2];
      uint32_t pk[8];
#pragma unroll
      for (int p = 0; p < 8; ++p) {
        int t1 = tq * 16 + p * 2;
        float e0 = gC * (bf2f(Th[(t1 + 0) * 72 + i2]) + bf2f(Tl[(t1 + 0) * 72 + i2]));
        float e1 = gC * (bf2f(Th[(t1 + 1) * 72 + i2]) + bf2f(Tl[(t1 + 1) * 72 + i2]));
        pk[p] = (uint32_t)f2bf(e0) | ((uint32_t)f2bf(e1) << 16);
      }
      *(uint4*)(eout + i2 * 64 + tq * 16) = make_uint4(pk[0], pk[1], pk[2], pk[3]);
      *(uint4*)(eout + i2 * 64 + tq * 16 + 8) = make_uint4(pk[4], pk[5], pk[6], pk[7]);
    }

    // M2 = M_s * Tinv  (3-term hi/lo bf16 MFMA)
    f32x4 m2acc[4] = {};
#pragma unroll
    for (int k0 = 0; k0 < 64; k0 += 32) {
      bf16x8 ah = *(const bf16x8*)&Mh[(16 * w + lr) * 72 + k0 + lk];
      bf16x8 al = *(const bf16x8*)&Ml[(16 * w + lr) * 72 + k0 + lk];
#pragma unroll
      for (int n = 0; n < 4; ++n) {
        bf16x8 bhf = *(const bf16x8*)&Th[(16 * n + lr) * 72 + k0 + lk];
        bf16x8 blf = *(const bf16x8*)&Tl[(16 * n + lr) * 72 + k0 + lk];
        m2acc[n] = __builtin_amdgcn_mfma_f32_16x16x32_bf16(ah, bhf, m2acc[n], 0, 0, 0);
        m2acc[n] = __builtin_amdgcn_mfma_f32_16x16x32_bf16(ah, blf, m2acc[n], 0, 0, 0);
        m2acc[n] = __builtin_amdgcn_mfma_f32_16x16x32_bf16(al, bhf, m2acc[n], 0, 0, 0);
      }
    }
#pragma unroll
    for (int n = 0; n < 4; ++n)
#pragma unroll
      for (int jj = 0; jj < 4; ++jj) {
        const int i = 16 * w + (l >> 4) * 4 + jj;
        const int j = 16 * n + lr;
        sM2[i * 72 + j] = f2bf(m2acc[n][jj]);
      }
    __syncthreads();
    {  // packed M2 copy out
      const int i2 = tid >> 2, tq = tid & 3;
      uint4 a0 = *(const uint4*)&sM2[i2 * 72 + tq * 16];
      uint4 a1 = *(const uint4*)&sM2[i2 * 72 + tq * 16 + 8];
      *(uint4*)(m2out + i2 * 64 + tq * 16) = a0;
      *(uint4*)(m2out + i2 * 64 + tq * 16 + 8) = a1;
    }
    __syncthreads();   // protect sM2 before next head
  }
}

// ---------------- MFMA chunked gated delta-rule scan (T=64) ----------------
// Fuses the output gate; Ktb columns XOR-swizzled by (dk>>5) to kill the
// 8-way transpose-scatter bank conflict (write col = t ^ (sq2<<4); read
// col-group = (k0+lk) ^ (w<<4) — same involution both sides).
__global__ __launch_bounds__(256) void scan_kernel(const uint16_t* __restrict__ Qn,
                                                   const uint16_t* __restrict__ Kn,
                                                   uint16_t* C1,
                                                   const uint8_t* __restrict__ coef) {
  __shared__ __align__(16) uint16_t Kb[64 * 136];
  __shared__ __align__(16) uint16_t Qb[64 * 136];
  __shared__ __align__(16) uint16_t Ktb[2][128 * 72];  // K^T [dk][t^], double-buffered
  __shared__ __align__(16) uint16_t M2b[64 * 72];
  __shared__ __align__(16) uint16_t Eb[64 * 72];
  __shared__ __align__(16) uint16_t Vb[64 * 24];
  __shared__ __align__(16) uint16_t Rt[16 * 72];     // R^T [v][t]
  __shared__ __align__(16) uint16_t D2t[16 * 72];    // D2^T [v][t]
  __shared__ __align__(16) uint16_t Sh[16 * 136];    // S^T hi [v][dk]
  __shared__ __align__(16) uint16_t Slo[16 * 136];   // S^T lo [v][dk]
  __shared__ float gABb[128];                        // gA[64] | gB[64]

  const int bid = blockIdx.x;
  const int kh = bid & 7;
  const int j2 = bid >> 3;
  const int sl = j2 >> 2;
  const int b = (j2 >> 1) & 1;
  const int h = kh * 2 + (j2 & 1);
  const int ch0 = (b * Hc + h) * NCH;

  const int tid = threadIdx.x;
  const int w = tid >> 6, l = tid & 63;
  const int lr = l & 15, lk = (l >> 4) * 8;
  const int row0 = 16 * w + (l >> 4) * 4;
  const int vcol = lr;
  const int sr = tid >> 2, sq2 = tid & 3;

  const size_t kqbase = (size_t)(b * Sc) * DQKc + kh * HDc;
  const size_t vbase = (size_t)(b * Sc) * NCATc + 2048 + h * HDc + sl * 16;
  uint16_t* Gb = C1 + (size_t)(b * Sc) * NCATc + 4096 + h * HDc + sl * 16 + vcol;

  float sreg[2][4] = {};
  uint4 kA[4], kB[4], qA[4], qB[4];
  ushort4 gv0, gv1;

  auto LOADS = [&](int cn, uint4 (&kd)[4], uint4 (&qd)[4], uint4 (&m2d)[2], uint4 (&ed)[2],
                   uint4& vd, float& gd, ushort4& gvd) {
    const size_t rb = kqbase + (size_t)(cn * CT + sr) * DQKc + sq2 * 32;
#pragma unroll
    for (int u = 0; u < 4; ++u) {
      kd[u] = *(const uint4*)(Kn + rb + u * 8);
      qd[u] = *(const uint4*)(Qn + rb + u * 8);
    }
    const uint16_t* cf = (const uint16_t*)(coef + (size_t)(ch0 + cn) * COEF_STRIDE);
#pragma unroll
    for (int e = 0; e < 2; ++e) {
      m2d[e] = *(const uint4*)(cf + sr * 64 + sq2 * 16 + e * 8);
      ed[e] = *(const uint4*)(cf + 4096 + sr * 64 + sq2 * 16 + e * 8);
    }
    if (tid < 128) {
      vd = *(const uint4*)(C1 + vbase + (size_t)(cn * CT + (tid >> 1)) * NCATc + (tid & 1) * 8);
      gd = ((const float*)(cf + 8192))[tid];
    }
    const uint16_t* gpre = Gb + (size_t)(cn * CT) * NCATc;
    gvd.x = gpre[(size_t)(row0 + 0) * NCATc];
    gvd.y = gpre[(size_t)(row0 + 1) * NCATc];
    gvd.z = gpre[(size_t)(row0 + 2) * NCATc];
    gvd.w = gpre[(size_t)(row0 + 3) * NCATc];
  };
  auto WSTAGE = [&](const uint4 (&kd)[4], const uint4 (&qd)[4], const uint4 (&m2d)[2],
                    const uint4 (&ed)[2], const uint4& vd, const float& gd) {
#pragma unroll
    for (int u = 0; u < 4; ++u) {
      *(uint4*)&Kb[sr * 136 + sq2 * 32 + u * 8] = kd[u];
      *(uint4*)&Qb[sr * 136 + sq2 * 32 + u * 8] = qd[u];
    }
#pragma unroll
    for (int e = 0; e < 2; ++e) {
      *(uint4*)&M2b[sr * 72 + sq2 * 16 + e * 8] = m2d[e];
      *(uint4*)&Eb[sr * 72 + sq2 * 16 + e * 8] = ed[e];
    }
    if (tid < 128) {
      *(uint4*)&Vb[(tid >> 1) * 24 + (tid & 1) * 8] = vd;
      gABb[tid] = gd;
    }
  };
  // K^T scatter with sq2-keyed column swizzle: value K[t=sr][dk] stored at
  // column sr ^ ((dk>>5)<<4); dk>>5 == sq2 for all dks this lane writes.
  auto SCAT = [&](uint16_t* Kt, const uint4 (&kd)[4], int u) {
    const int c0 = sq2 * 32 + u * 8;
    const int tsw = sr ^ (sq2 << 4);
    uint32_t x0 = kd[u].x, x1 = kd[u].y, x2 = kd[u].z, x3 = kd[u].w;
    Kt[(c0 + 0) * 72 + tsw] = (uint16_t)x0; Kt[(c0 + 1) * 72 + tsw] = (uint16_t)(x0 >> 16);
    Kt[(c0 + 2) * 72 + tsw] = (uint16_t)x1; Kt[(c0 + 3) * 72 + tsw] = (uint16_t)(x1 >> 16);
    Kt[(c0 + 4) * 72 + tsw] = (uint16_t)x2; Kt[(c0 + 5) * 72 + tsw] = (uint16_t)(x2 >> 16);
    Kt[(c0 + 6) * 72 + tsw] = (uint16_t)x3; Kt[(c0 + 7) * 72 + tsw] = (uint16_t)(x3 >> 16);
  };

  auto CHUNK = [&](int c, bool pre, uint4 (&kcur)[4], uint4 (&knxt)[4],
                   uint4 (&qcur)[4], uint4 (&qnxt)[4], ushort4& gvcur, ushort4& gvnxt) {
    uint4 m2d[2], ed[2]; uint4 vd; float gd = 0.f;
    if (pre) LOADS(c + 1, knxt, qnxt, m2d, ed, vd, gd, gvnxt);
    const uint16_t* Ktc = Ktb[c & 1];
    uint16_t* Ktn = Ktb[(c + 1) & 1];

    // --- Phase A: P = K*S, Pq = Q*S, R = V - gA*P ---
    f32x4 accP = {0, 0, 0, 0}, accPq = {0, 0, 0, 0};
#pragma unroll
    for (int k0 = 0; k0 < 128; k0 += 32) {
      bf16x8 ka = *(const bf16x8*)&Kb[(16 * w + lr) * 136 + k0 + lk];
      bf16x8 qa = *(const bf16x8*)&Qb[(16 * w + lr) * 136 + k0 + lk];
      bf16x8 shf = *(const bf16x8*)&Sh[lr * 136 + k0 + lk];
      bf16x8 slf = *(const bf16x8*)&Slo[lr * 136 + k0 + lk];
      accP = __builtin_amdgcn_mfma_f32_16x16x32_bf16(ka, shf, accP, 0, 0, 0);
      accP = __builtin_amdgcn_mfma_f32_16x16x32_bf16(ka, slf, accP, 0, 0, 0);
      accPq = __builtin_amdgcn_mfma_f32_16x16x32_bf16(qa, shf, accPq, 0, 0, 0);
      accPq = __builtin_amdgcn_mfma_f32_16x16x32_bf16(qa, slf, accPq, 0, 0, 0);
    }
    {
      float rv[4];
#pragma unroll
      for (int j = 0; j < 4; ++j) {
        float vv = bf2f(Vb[(row0 + j) * 24 + vcol]);
        float ga = gABb[row0 + j];
        rv[j] = vv - ga * accP[j];
      }
      uint32_t r01 = (uint32_t)f2bf(rv[0]) | ((uint32_t)f2bf(rv[1]) << 16);
      uint32_t r23 = (uint32_t)f2bf(rv[2]) | ((uint32_t)f2bf(rv[3]) << 16);
      *(uint2*)&Rt[vcol * 72 + row0] = make_uint2(r01, r23);
    }
    __syncthreads();

    // --- Phase B: D2 = E*R, O = gB*Pq + M2*R, gated bf16 store (in-place G) ---
    f32x4 accD2 = {0, 0, 0, 0}, accO = {0, 0, 0, 0};
#pragma unroll
    for (int k0 = 0; k0 < 64; k0 += 32) {
      bf16x8 rb8 = *(const bf16x8*)&Rt[lr * 72 + k0 + lk];
      bf16x8 ea = *(const bf16x8*)&Eb[(16 * w + lr) * 72 + k0 + lk];
      bf16x8 ma = *(const bf16x8*)&M2b[(16 * w + lr) * 72 + k0 + lk];
      accD2 = __builtin_amdgcn_mfma_f32_16x16x32_bf16(ea, rb8, accD2, 0, 0, 0);
      accO = __builtin_amdgcn_mfma_f32_16x16x32_bf16(ma, rb8, accO, 0, 0, 0);
    }
    if (pre) { SCAT(Ktn, knxt, 0); SCAT(Ktn, knxt, 1); }
    {
      uint16_t* gp = Gb + (size_t)(c * CT) * NCATc;
      uint16_t gvv[4] = {gvcur.x, gvcur.y, gvcur.z, gvcur.w};
#pragma unroll
      for (int j = 0; j < 4; ++j) {
        float o = gABb[64 + row0 + j] * accPq[j] + accO[j];
        float gg = sigmoidf_(bf2f(gvv[j]));
        gp[(size_t)(row0 + j) * NCATc] = f2bf(o * gg);
      }
      uint32_t d01 = (uint32_t)f2bf(accD2[0]) | ((uint32_t)f2bf(accD2[1]) << 16);
      uint32_t d23 = (uint32_t)f2bf(accD2[2]) | ((uint32_t)f2bf(accD2[3]) << 16);
      *(uint2*)&D2t[vcol * 72 + row0] = make_uint2(d01, d23);
    }
    __syncthreads();

    // --- Phase C: dS = K^T*D2, S = gT*S + dS, stage chunk c+1 ---
    const float gT = gABb[127];
    f32x4 accY[2] = {{0, 0, 0, 0}, {0, 0, 0, 0}};
#pragma unroll
    for (int k0 = 0; k0 < 64; k0 += 32) {
      const int ksw = (k0 + lk) ^ (w << 4);    // read-side swizzle, key = dk>>5 = w
      bf16x8 db = *(const bf16x8*)&D2t[lr * 72 + k0 + lk];
      bf16x8 ka0 = *(const bf16x8*)&Ktc[(32 * w + lr) * 72 + ksw];
      bf16x8 ka1 = *(const bf16x8*)&Ktc[(32 * w + 16 + lr) * 72 + ksw];
      accY[0] = __builtin_amdgcn_mfma_f32_16x16x32_bf16(ka0, db, accY[0], 0, 0, 0);
      accY[1] = __builtin_amdgcn_mfma_f32_16x16x32_bf16(ka1, db, accY[1], 0, 0, 0);
    }
    if (pre) { SCAT(Ktn, knxt, 2); SCAT(Ktn, knxt, 3); }
#pragma unroll
    for (int m = 0; m < 2; ++m) {
      uint16_t hi[4], lo[4];
#pragma unroll
      for (int j = 0; j < 4; ++j) {
        float s = gT * sreg[m][j] + accY[m][j];
        sreg[m][j] = s;
        hi[j] = f2bf(s);
        lo[j] = f2bf(s - bf2f(hi[j]));
      }
      const int dk0 = 32 * w + m * 16 + (l >> 4) * 4;
      *(uint2*)&Sh[vcol * 136 + dk0] =
          make_uint2((uint32_t)hi[0] | ((uint32_t)hi[1] << 16),
                     (uint32_t)hi[2] | ((uint32_t)hi[3] << 16));
      *(uint2*)&Slo[vcol * 136 + dk0] =
          make_uint2((uint32_t)lo[0] | ((uint32_t)lo[1] << 16),
                     (uint32_t)lo[2] | ((uint32_t)lo[3] << 16));
    }
    if (pre) WSTAGE(knxt, qnxt, m2d, ed, vd, gd);
    __syncthreads();
  };

  // prologue: stage chunk 0, zero S, scatter chunk 0's K^T
  {
    uint4 m2d[2], ed[2]; uint4 vd; float gd = 0.f;
    LOADS(0, kA, qA, m2d, ed, vd, gd, gv0);
    WSTAGE(kA, qA, m2d, ed, vd, gd);
#pragma unroll
    for (int u = 0; u < 4; ++u) SCAT(Ktb[0], kA, u);
  }
  for (int i = tid; i < 16 * 136; i += 256) { Sh[i] = 0; Slo[i] = 0; }
  __syncthreads();

  for (int c2 = 0; c2 < NCH; c2 += 2) {
    CHUNK(c2, true, kA, kB, qA, qB, gv0, gv1);
    CHUNK(c2 + 1, c2 + 2 < NCH, kB, kA, qB, qA, gv1, gv0);
  }
}

extern "C" void kernel_launch(void* const* d_in, const int* in_sizes, int n_in,
                              void* d_out, int out_size, void* d_ws, size_t ws_size,
                              hipStream_t stream) {
  (void)in_sizes; (void)n_in; (void)out_size; (void)ws_size;
  const float* x     = (const float*)d_in[0];
  const float* wq    = (const float*)d_in[1];
  const float* wk    = (const float*)d_in[2];
  const float* wv    = (const float*)d_in[3];
  const float* wo    = (const float*)d_in[4];
  const float* qcw   = (const float*)d_in[5];
  const float* kcw   = (const float*)d_in[6];
  const float* aw    = (const float*)d_in[7];
  const float* abias = (const float*)d_in[8];
  const float* bw    = (const float*)d_in[9];
  const float* bbias = (const float*)d_in[10];
  const float* gw    = (const float*)d_in[11];
  const float* nqw   = (const float*)d_in[12];
  const float* nkw   = (const float*)d_in[13];

  // workspace layout (bytes), total ~202 MiB
  uint8_t* ws = (uint8_t*)d_ws;
  uint16_t* xb   = (uint16_t*)(ws);                 //  33,554,432  x bf16
  uint16_t* wcat = (uint16_t*)(ws + 33554432);      //  25,165,824  [wq;wk;wv;g_w] bf16
  uint16_t* wob  = (uint16_t*)(ws + 58720256);      //   8,388,608  wo bf16
  uint16_t* c1   = (uint16_t*)(ws + 67108864);      // 100,663,296  x@Wcat^T bf16 (8192x6144)
  float*    abuf = (float*)   (ws + 167772160);     //   1,048,576  alpha|beta
  uint16_t* qn   = (uint16_t*)(ws + 168820736);     //  16,777,216  normed Q bf16
  uint16_t* kn   = (uint16_t*)(ws + 185597952);     //  16,777,216  normed K bf16
  uint8_t*  cofs = (uint8_t*)ws;                    // coef overlays xb+wcat (dead after GEMM1)

  cast_kernel<<<2048, 256, 0, stream>>>(x, xb, Mc * Dc / 4);
  cast_kernel<<<1024, 256, 0, stream>>>(wq, wcat, DQKc * Dc / 4);
  cast_kernel<<<1024, 256, 0, stream>>>(wk, wcat + DQKc * Dc, DQKc * Dc / 4);
  cast_kernel<<<1024, 256, 0, stream>>>(wv, wcat + 2 * DQKc * Dc, DVc * Dc / 4);
  cast_kernel<<<1024, 256, 0, stream>>>(gw, wcat + 2 * DQKc * Dc + DVc * Dc, DVc * Dc / 4);
  cast_kernel<<<1024, 256, 0, stream>>>(wo, wob, DVc * Dc / 4);

  gemm256_bt<uint16_t><<<768, 512, 0, stream>>>(xb, wcat, c1, NCATc, Dc, Dc);   // QKVG
  alphabeta_kernel<<<2048, 256, 0, stream>>>(x, aw, abias, bw, bbias, abuf);
  convnorm_kernel<<<16384, 256, 0, stream>>>(c1, qcw, kcw, nqw, nkw, qn, kn);
  scores_kernel<<<1024, 256, 0, stream>>>(qn, kn, abuf, cofs);                  // chunk coefs
  scan_kernel<<<256, 256, 0, stream>>>(qn, kn, c1, cofs);                       // gated O -> c1 G-section
  gemm256_bt<float><<<256, 512, 0, stream>>>(c1 + 4096, wob, (float*)d_out, DVc, Dc, NCATc);
}